// Round 7
// baseline (791.430 us; speedup 1.0000x reference)
//
#include <hip/hip_runtime.h>
#include <hip/hip_bf16.h>

#define S_TOT 5440
#define C_DIM 256
#define F_DIM 1024
#define N_LAYERS 6

__device__ __constant__ int c_HW[4]    = {64, 32, 16, 8};
__device__ __constant__ int c_logW[4]  = {6, 5, 4, 3};
__device__ __constant__ int c_start[4] = {0, 4096, 5120, 5376};

typedef __attribute__((ext_vector_type(8))) short bf16x8;
typedef __attribute__((ext_vector_type(4))) float f32x4;

__device__ __forceinline__ short f2bf(float f) {
    __hip_bfloat16 h = __float2bfloat16(f);
    return *reinterpret_cast<short*>(&h);
}
__device__ __forceinline__ float bf2f(unsigned short u) {
    union { unsigned int i; float f; } c; c.i = ((unsigned int)u) << 16; return c.f;
}

// ---------------- weight prep: fp32 [K][N] -> bf16 [N][K], all 36 matrices ----------------
__global__ __launch_bounds__(256) void prep_weights(
    const float* __restrict__ Wv, const float* __restrict__ Woff,
    const float* __restrict__ Wattn, const float* __restrict__ Wout,
    const float* __restrict__ W1, const float* __restrict__ W2,
    unsigned short* __restrict__ WT)
{
    __shared__ short T[64][72];
    const int bid = blockIdx.x;
    const int layer = bid / 184;
    const int r = bid % 184;
    const float* src; unsigned short* dst; int K, N, kb, nb;
    if (r < 16)       { src = Wv    + (long)layer*65536;  dst = WT + 0       + (long)layer*65536;  K=256;  N=256;  kb=r&3;        nb=r>>2; }
    else if (r < 32)  { src = Woff  + (long)layer*65536;  dst = WT + 393216  + (long)layer*65536;  K=256;  N=256;  kb=(r-16)&3;   nb=(r-16)>>2; }
    else if (r < 40)  { src = Wattn + (long)layer*32768;  dst = WT + 786432  + (long)layer*32768;  K=256;  N=128;  kb=(r-32)&3;   nb=(r-32)>>2; }
    else if (r < 56)  { src = Wout  + (long)layer*65536;  dst = WT + 983040  + (long)layer*65536;  K=256;  N=256;  kb=(r-40)&3;   nb=(r-40)>>2; }
    else if (r < 120) { src = W1    + (long)layer*262144; dst = WT + 1376256 + (long)layer*262144; K=256;  N=1024; kb=(r-56)&3;   nb=(r-56)>>2; }
    else              { src = W2    + (long)layer*262144; dst = WT + 2949120 + (long)layer*262144; K=1024; N=256;  kb=(r-120)&15; nb=(r-120)>>4; }
    const int k0 = kb * 64, n0 = nb * 64;
    const int t = threadIdx.x;
    {
        const int row = t >> 2, cg = (t & 3) * 16;
        const float* sp = src + (long)(k0 + row) * N + n0 + cg;
        float4 v0 = *(const float4*)sp;
        float4 v1 = *(const float4*)(sp + 4);
        float4 v2 = *(const float4*)(sp + 8);
        float4 v3 = *(const float4*)(sp + 12);
        short tmp[16];
        tmp[0]=f2bf(v0.x); tmp[1]=f2bf(v0.y); tmp[2]=f2bf(v0.z); tmp[3]=f2bf(v0.w);
        tmp[4]=f2bf(v1.x); tmp[5]=f2bf(v1.y); tmp[6]=f2bf(v1.z); tmp[7]=f2bf(v1.w);
        tmp[8]=f2bf(v2.x); tmp[9]=f2bf(v2.y); tmp[10]=f2bf(v2.z); tmp[11]=f2bf(v2.w);
        tmp[12]=f2bf(v3.x); tmp[13]=f2bf(v3.y); tmp[14]=f2bf(v3.z); tmp[15]=f2bf(v3.w);
        *(bf16x8*)&T[row][cg]     = *(bf16x8*)&tmp[0];
        *(bf16x8*)&T[row][cg + 8] = *(bf16x8*)&tmp[8];
    }
    __syncthreads();
    {
        const int n = t >> 2, kg = (t & 3) * 16;
        short o[16];
        #pragma unroll
        for (int j = 0; j < 16; ++j) o[j] = T[kg + j][n];
        unsigned short* dp = dst + (long)(n0 + n) * K + k0 + kg;
        *(bf16x8*)dp       = *(bf16x8*)&o[0];
        *(bf16x8*)(dp + 8) = *(bf16x8*)&o[8];
    }
}

// ============ A-prep: load fp32 64x256 tile, optional LN, optional +pos, -> bf16 LDS ============
__device__ __forceinline__ void prep_A(
    const float* __restrict__ Ain, const float* __restrict__ g,
    const float* __restrict__ b, const float* __restrict__ pos,
    float* __restrict__ xout, int mBase, int doLN,
    short (*As)[264])
{
    const int t = threadIdx.x;
    const int row = t >> 2, q4 = t & 3;
    const long gbase = (long)(mBase + row) * 256 + q4 * 64;
    float va[64];
    #pragma unroll
    for (int j = 0; j < 16; ++j) {
        float4 v = *(const float4*)(Ain + gbase + j * 4);
        va[j*4+0] = v.x; va[j*4+1] = v.y; va[j*4+2] = v.z; va[j*4+3] = v.w;
    }
    if (doLN) {
        float s1 = 0.f, s2 = 0.f;
        #pragma unroll
        for (int j = 0; j < 64; ++j) { s1 += va[j]; s2 += va[j] * va[j]; }
        s1 += __shfl_xor(s1, 1); s2 += __shfl_xor(s2, 1);
        s1 += __shfl_xor(s1, 2); s2 += __shfl_xor(s2, 2);
        const float mean = s1 * (1.f / 256.f);
        const float var  = s2 * (1.f / 256.f) - mean * mean;
        const float rstd = rsqrtf(var + 1e-5f);
        #pragma unroll
        for (int j = 0; j < 16; ++j) {
            float4 g4 = *(const float4*)(g + q4 * 64 + j * 4);
            float4 b4 = *(const float4*)(b + q4 * 64 + j * 4);
            va[j*4+0] = (va[j*4+0] - mean) * rstd * g4.x + b4.x;
            va[j*4+1] = (va[j*4+1] - mean) * rstd * g4.y + b4.y;
            va[j*4+2] = (va[j*4+2] - mean) * rstd * g4.z + b4.z;
            va[j*4+3] = (va[j*4+3] - mean) * rstd * g4.w + b4.w;
        }
    }
    if (xout) {
        #pragma unroll
        for (int j = 0; j < 16; ++j) {
            float4 v;
            v.x = va[j*4+0]; v.y = va[j*4+1]; v.z = va[j*4+2]; v.w = va[j*4+3];
            *(float4*)(xout + gbase + j * 4) = v;
        }
    }
    if (pos) {
        #pragma unroll
        for (int j = 0; j < 16; ++j) {
            float4 p = *(const float4*)(pos + gbase + j * 4);
            va[j*4+0] += p.x; va[j*4+1] += p.y; va[j*4+2] += p.z; va[j*4+3] += p.w;
        }
    }
    #pragma unroll
    for (int j8 = 0; j8 < 8; ++j8) {
        short tmp[8];
        #pragma unroll
        for (int e = 0; e < 8; ++e) tmp[e] = f2bf(va[j8 * 8 + e]);
        *(bf16x8*)&As[row][q4 * 64 + j8 * 8] = *(bf16x8*)tmp;
    }
}

// ============ GEMM core with A resident in LDS (K=256), B streamed ============
template<int NF>
__device__ __forceinline__ void core_Alds(
    const unsigned short* __restrict__ Bt, int nBase,
    const short (*As)[264], short (*Bs)[72], f32x4 (&acc)[2][NF])
{
    const int t = threadIdx.x;
    const int lane = t & 63, wave = t >> 6;
    const int wr = wave >> 1, wc = wave & 1;
    const int lr = lane & 15;

    #pragma unroll
    for (int i = 0; i < 2; ++i)
        #pragma unroll
        for (int j = 0; j < NF; ++j)
            acc[i][j] = (f32x4){0.f, 0.f, 0.f, 0.f};

    for (int k0 = 0; k0 < 256; k0 += 64) {
        bf16x8 rb[NF];
        #pragma unroll
        for (int q = 0; q < NF; ++q) {
            int flat = q * 256 + t, row = flat >> 3, cg = (flat & 7) * 8;
            rb[q] = *(const bf16x8*)(Bt + (long)(nBase + row) * 256 + k0 + cg);
        }
        __syncthreads();
        #pragma unroll
        for (int q = 0; q < NF; ++q) {
            int flat = q * 256 + t, row = flat >> 3, cg = (flat & 7) * 8;
            *(bf16x8*)&Bs[row][cg] = rb[q];
        }
        __syncthreads();
        #pragma unroll
        for (int kk = 0; kk < 2; ++kk) {
            const int lks = kk * 32 + (lane >> 4) * 8;
            bf16x8 af[2], bfr[NF];
            #pragma unroll
            for (int fm = 0; fm < 2; ++fm)
                af[fm] = *(const bf16x8*)&As[wr * 32 + fm * 16 + lr][k0 + lks];
            #pragma unroll
            for (int fn = 0; fn < NF; ++fn)
                bfr[fn] = *(bf16x8*)&Bs[wc * (NF * 16) + fn * 16 + lr][lks];
            #pragma unroll
            for (int fm = 0; fm < 2; ++fm)
                #pragma unroll
                for (int fn = 0; fn < NF; ++fn)
                    acc[fm][fn] = __builtin_amdgcn_mfma_f32_16x16x32_bf16(
                        af[fm], bfr[fn], acc[fm][fn], 0, 0, 0);
        }
    }
}

// ---------------- fused LN2 + projections (grid 85 x 5) ----------------
__global__ __launch_bounds__(256) void proj_ln(
    const float* __restrict__ Ain, const float* __restrict__ pos,
    const float* __restrict__ g, const float* __restrict__ b,
    const unsigned short* __restrict__ WvT, const float* __restrict__ bv,
    const unsigned short* __restrict__ WofT, const float* __restrict__ bof,
    const unsigned short* __restrict__ WatT, const float* __restrict__ bat,
    unsigned short* __restrict__ value_bf, float* __restrict__ offraw,
    float* __restrict__ logits, float* __restrict__ xcur, int doLN)
{
    __shared__ short As[64][264];
    __shared__ short Bs[128][72];
    const int ny = blockIdx.y, mBase = blockIdx.x * 64;
    const unsigned short* Bp; const float* bias; int nBase, kind;
    if (ny < 2)      { Bp = WvT;  bias = bv;  nBase = ny * 128;       kind = 0; }
    else if (ny < 4) { Bp = WofT; bias = bof; nBase = (ny - 2) * 128; kind = 1; }
    else             { Bp = WatT; bias = bat; nBase = 0;              kind = 2; }

    prep_A(Ain, g, b, (kind > 0) ? pos : nullptr,
           (doLN && ny == 0) ? xcur : nullptr, mBase, doLN, As);

    f32x4 acc[2][4];
    core_Alds<4>(Bp, nBase, As, Bs, acc);

    const int lane = threadIdx.x & 63, wave = threadIdx.x >> 6;
    const int wr = wave >> 1, wc = wave & 1;
    #pragma unroll
    for (int fm = 0; fm < 2; ++fm)
        #pragma unroll
        for (int fn = 0; fn < 4; ++fn)
            #pragma unroll
            for (int r = 0; r < 4; ++r) {
                int m = mBase + wr * 32 + fm * 16 + (lane >> 4) * 4 + r;
                int n = nBase + wc * 64 + fn * 16 + (lane & 15);
                float v = acc[fm][fn][r] + bias[n];
                if (kind == 0)      value_bf[(long)m * 256 + n] = (unsigned short)f2bf(v);
                else if (kind == 1) offraw[(long)m * 256 + n] = v;
                else                logits[(long)m * 128 + n] = v;
            }
}

// ============ 16-row wave GEMM: wave computes 16 x 64 at nBase; A in LDS, B global ============
template<int KSTEPS, int LDA>
__device__ __forceinline__ void mm16(
    const short* __restrict__ A, const unsigned short* __restrict__ Bt,
    int ldb, int nBase, f32x4 (&acc)[4], int lane)
{
    const int lr = lane & 15, kg = (lane >> 4) * 8;
    #pragma unroll
    for (int j = 0; j < 4; ++j) acc[j] = (f32x4){0.f, 0.f, 0.f, 0.f};
    for (int ks = 0; ks < KSTEPS; ++ks) {
        #pragma unroll
        for (int kk = 0; kk < 2; ++kk) {
            const int k = ks * 64 + kk * 32 + kg;
            bf16x8 af = *(const bf16x8*)&A[lr * LDA + k];
            bf16x8 bf0 = *(const bf16x8*)(Bt + (long)(nBase + 0  + lr) * ldb + k);
            bf16x8 bf1 = *(const bf16x8*)(Bt + (long)(nBase + 16 + lr) * ldb + k);
            bf16x8 bf2 = *(const bf16x8*)(Bt + (long)(nBase + 32 + lr) * ldb + k);
            bf16x8 bf3 = *(const bf16x8*)(Bt + (long)(nBase + 48 + lr) * ldb + k);
            acc[0] = __builtin_amdgcn_mfma_f32_16x16x32_bf16(af, bf0, acc[0], 0, 0, 0);
            acc[1] = __builtin_amdgcn_mfma_f32_16x16x32_bf16(af, bf1, acc[1], 0, 0, 0);
            acc[2] = __builtin_amdgcn_mfma_f32_16x16x32_bf16(af, bf2, acc[2], 0, 0, 0);
            acc[3] = __builtin_amdgcn_mfma_f32_16x16x32_bf16(af, bf3, acc[3], 0, 0, 0);
        }
    }
}

// ---------------- fused msda + Wout + LN1 + W1 + W2 (grid 340, 16 rows/block) ----------------
__global__ __launch_bounds__(256) void layer_post(
    const unsigned short* __restrict__ value, const float* __restrict__ offraw,
    const float* __restrict__ logits, const float* __restrict__ vr,
    const float* __restrict__ res,
    const unsigned short* __restrict__ WouT, const float* __restrict__ bout,
    const float* __restrict__ ln1g, const float* __restrict__ ln1b,
    const unsigned short* __restrict__ W1T, const float* __restrict__ b1,
    const unsigned short* __restrict__ W2T, const float* __restrict__ b2,
    float* __restrict__ out)
{
    // sH: stage A = coord scratch (sIdx 16KB + sW 16KB); stage C/D = hidden [16][1032] bf16
    __shared__ __align__(16) short sH[16][1032];     // 33024 B
    __shared__ __align__(16) short sM[16][264];      // msda out bf16
    __shared__ __align__(16) short sA1[16][264];     // LN1 out bf16
    __shared__ float2 sRed[4][16];
    __shared__ float2 sMR[16];

    const int t = threadIdx.x;
    const int sBase = blockIdx.x * 16;
    const int lane = t & 63, wave = t >> 6;
    const int lr = lane & 15, rowg = (lane >> 4) * 4;

    // ===== Stage A: msda for 16 queries, 2 chunks of 8 =====
    int4*   sIdx = (int4*)&sH[0][0];
    float4* sWt  = (float4*)((char*)&sH[0][0] + 16384);
    for (int c = 0; c < 2; ++c) {
        #pragma unroll
        for (int it = 0; it < 4; ++it) {
            const int id = it * 256 + t;
            const int q = id >> 7, tt = id & 127;
            const int s = sBase + c * 8 + q;
            const int pt = tt & 15, l = pt >> 2;

            float lg = logits[(long)s * 128 + tt];
            float m = lg;
            #pragma unroll
            for (int o = 1; o < 16; o <<= 1) m = fmaxf(m, __shfl_xor(m, o));
            float e = expf(lg - m);
            float sum = e;
            #pragma unroll
            for (int o = 1; o < 16; o <<= 1) sum += __shfl_xor(sum, o);
            float aw = e / sum;

            int ls = (s < 4096) ? 0 : (s < 5120) ? 1 : (s < 5376) ? 2 : 3;
            int lw = c_logW[ls];
            int Wq = c_HW[ls];
            int rem = s - c_start[ls];
            int qi = rem >> lw, qj = rem & (Wq - 1);
            float xh = (qj + 0.5f) / (vr[ls * 2 + 1] * (float)Wq);
            float yh = (qi + 0.5f) / (vr[ls * 2 + 0] * (float)Wq);

            const int Wl = c_HW[l], sl = c_start[l];
            const float fW = (float)Wl;
            float refx = xh * vr[l * 2 + 1];
            float refy = yh * vr[l * 2 + 0];
            float2 oxy = *(const float2*)(offraw + (long)s * 256 + tt * 2);
            float x = refx * fW + oxy.x - 0.5f;
            float y = refy * fW + oxy.y - 0.5f;
            float x0f = floorf(x), y0f = floorf(y);
            float fx = x - x0f, fy = y - y0f;
            int x0 = (int)x0f, y0 = (int)y0f;
            int x1 = x0 + 1, y1 = y0 + 1;
            float vx0 = (x0 >= 0 && x0 < Wl) ? 1.f : 0.f;
            float vx1 = (x1 >= 0 && x1 < Wl) ? 1.f : 0.f;
            float vy0 = (y0 >= 0 && y0 < Wl) ? 1.f : 0.f;
            float vy1 = (y1 >= 0 && y1 < Wl) ? 1.f : 0.f;
            int cx0 = min(max(x0, 0), Wl - 1), cx1 = min(max(x1, 0), Wl - 1);
            int cy0 = min(max(y0, 0), Wl - 1), cy1 = min(max(y1, 0), Wl - 1);

            int4 id4;
            id4.x = sl + cy0 * Wl + cx0;
            id4.y = sl + cy0 * Wl + cx1;
            id4.z = sl + cy1 * Wl + cx0;
            id4.w = sl + cy1 * Wl + cx1;
            sIdx[q * 128 + tt] = id4;
            float4 w4;
            w4.x = aw * (1.f - fx) * (1.f - fy) * vx0 * vy0;
            w4.y = aw * fx * (1.f - fy) * vx1 * vy0;
            w4.z = aw * (1.f - fx) * fy * vx0 * vy1;
            w4.w = aw * fx * fy * vx1 * vy1;
            sWt[q * 128 + tt] = w4;
        }
        __syncthreads();
        {
            const int q2 = t >> 5, h = (t >> 2) & 7, dq = t & 3;
            const int cb = h * 32 + dq * 8;
            float a8[8] = {0.f,0.f,0.f,0.f,0.f,0.f,0.f,0.f};
            #pragma unroll
            for (int pt = 0; pt < 16; ++pt) {
                int4 id = sIdx[q2 * 128 + h * 16 + pt];
                float4 w = sWt[q2 * 128 + h * 16 + pt];
                bf16x8 u0 = *(const bf16x8*)(value + (long)id.x * 256 + cb);
                bf16x8 u1 = *(const bf16x8*)(value + (long)id.y * 256 + cb);
                bf16x8 u2 = *(const bf16x8*)(value + (long)id.z * 256 + cb);
                bf16x8 u3 = *(const bf16x8*)(value + (long)id.w * 256 + cb);
                #pragma unroll
                for (int e8 = 0; e8 < 8; ++e8)
                    a8[e8] += w.x * bf2f((unsigned short)u0[e8])
                            + w.y * bf2f((unsigned short)u1[e8])
                            + w.z * bf2f((unsigned short)u2[e8])
                            + w.w * bf2f((unsigned short)u3[e8]);
            }
            short o8[8];
            #pragma unroll
            for (int e8 = 0; e8 < 8; ++e8) o8[e8] = f2bf(a8[e8]);
            *(bf16x8*)&sM[c * 8 + q2][cb] = *(bf16x8*)o8;
        }
        __syncthreads();
    }

    // ===== Stage B: Wout GEMM (16x256) + bias + res, LN1 stats =====
    f32x4 acc[4];
    mm16<4, 264>(&sM[0][0], WouT, 256, wave * 64, acc, lane);

    float bias_c[4];
    int ncol[4];
    #pragma unroll
    for (int fn = 0; fn < 4; ++fn) {
        ncol[fn] = wave * 64 + fn * 16 + lr;
        bias_c[fn] = bout[ncol[fn]];
    }
    #pragma unroll
    for (int fn = 0; fn < 4; ++fn)
        #pragma unroll
        for (int r = 0; r < 4; ++r)
            acc[fn][r] += bias_c[fn] + res[(long)(sBase + rowg + r) * 256 + ncol[fn]];

    #pragma unroll
    for (int r = 0; r < 4; ++r) {
        float s1 = acc[0][r] + acc[1][r] + acc[2][r] + acc[3][r];
        float s2 = acc[0][r]*acc[0][r] + acc[1][r]*acc[1][r]
                 + acc[2][r]*acc[2][r] + acc[3][r]*acc[3][r];
        #pragma unroll
        for (int o = 1; o < 16; o <<= 1) {
            s1 += __shfl_xor(s1, o);
            s2 += __shfl_xor(s2, o);
        }
        if (lr == 0) { float2 pr; pr.x = s1; pr.y = s2; sRed[wave][rowg + r] = pr; }
    }
    __syncthreads();
    if (t < 16) {
        float2 a0 = sRed[0][t], a1 = sRed[1][t], a2 = sRed[2][t], a3 = sRed[3][t];
        float mean = (a0.x + a1.x + a2.x + a3.x) * (1.f / 256.f);
        float var  = (a0.y + a1.y + a2.y + a3.y) * (1.f / 256.f) - mean * mean;
        float2 mr; mr.x = mean; mr.y = rsqrtf(var + 1e-5f);
        sMR[t] = mr;
    }
    __syncthreads();

    f32x4 lnv[4];
    {
        float g_c[4], b_c[4];
        #pragma unroll
        for (int fn = 0; fn < 4; ++fn) { g_c[fn] = ln1g[ncol[fn]]; b_c[fn] = ln1b[ncol[fn]]; }
        #pragma unroll
        for (int r = 0; r < 4; ++r) {
            float2 mr = sMR[rowg + r];
            #pragma unroll
            for (int fn = 0; fn < 4; ++fn)
                lnv[fn][r] = (acc[fn][r] - mr.x) * mr.y * g_c[fn] + b_c[fn];
        }
        #pragma unroll
        for (int fn = 0; fn < 4; ++fn)
            #pragma unroll
            for (int r = 0; r < 4; ++r)
                sA1[rowg + r][ncol[fn]] = f2bf(lnv[fn][r]);
    }
    __syncthreads();

    // ===== Stage C: W1 + relu -> hidden (LDS) =====
    #pragma unroll
    for (int nc = 0; nc < 4; ++nc) {
        f32x4 h4[4];
        mm16<4, 264>(&sA1[0][0], W1T, 256, nc * 256 + wave * 64, h4, lane);
        #pragma unroll
        for (int fn = 0; fn < 4; ++fn) {
            int n = nc * 256 + wave * 64 + fn * 16 + lr;
            float bb = b1[n];
            #pragma unroll
            for (int r = 0; r < 4; ++r)
                sH[rowg + r][n] = f2bf(fmaxf(h4[fn][r] + bb, 0.f));
        }
    }
    __syncthreads();

    // ===== Stage D: W2 + b2 + lnv -> out =====
    f32x4 o4[4];
    mm16<16, 1032>(&sH[0][0], W2T, 1024, wave * 64, o4, lane);
    #pragma unroll
    for (int fn = 0; fn < 4; ++fn) {
        float bb = b2[ncol[fn]];
        #pragma unroll
        for (int r = 0; r < 4; ++r)
            out[(long)(sBase + rowg + r) * 256 + ncol[fn]] = o4[fn][r] + bb + lnv[fn][r];
    }
}

// ---------------- final LayerNorm: one wave per row ----------------
__global__ __launch_bounds__(256) void ln4f(
    const float* __restrict__ in, const float* __restrict__ g,
    const float* __restrict__ b, float* __restrict__ out)
{
    const int wave = threadIdx.x >> 6, lane = threadIdx.x & 63;
    const int s = blockIdx.x * 4 + wave;
    f32x4 v = *(const f32x4*)(in + (long)s * 256 + lane * 4);

    float sum = v[0] + v[1] + v[2] + v[3];
    #pragma unroll
    for (int o = 1; o < 64; o <<= 1) sum += __shfl_xor(sum, o);
    const float mean = sum * (1.f / 256.f);

    f32x4 d = v - mean;
    float sq = d[0]*d[0] + d[1]*d[1] + d[2]*d[2] + d[3]*d[3];
    #pragma unroll
    for (int o = 1; o < 64; o <<= 1) sq += __shfl_xor(sq, o);
    const float rstd = rsqrtf(sq * (1.f / 256.f) + 1e-5f);

    f32x4 gg = *(const f32x4*)(g + lane * 4);
    f32x4 bb = *(const f32x4*)(b + lane * 4);
    f32x4 o4 = d * rstd * gg + bb;
    *(f32x4*)(out + (long)s * 256 + lane * 4) = o4;
}

extern "C" void kernel_launch(void* const* d_in, const int* in_sizes, int n_in,
                              void* d_out, int out_size, void* d_ws, size_t ws_size,
                              hipStream_t stream) {
    const float* src   = (const float*)d_in[0];
    const float* pos   = (const float*)d_in[1];
    const float* vr    = (const float*)d_in[2];
    const float* Wv    = (const float*)d_in[5];
    const float* bv    = (const float*)d_in[6];
    const float* Woff  = (const float*)d_in[7];
    const float* boff  = (const float*)d_in[8];
    const float* Wattn = (const float*)d_in[9];
    const float* battn = (const float*)d_in[10];
    const float* Wout  = (const float*)d_in[11];
    const float* bout  = (const float*)d_in[12];
    const float* ln1g  = (const float*)d_in[13];
    const float* ln1b  = (const float*)d_in[14];
    const float* W1    = (const float*)d_in[15];
    const float* b1    = (const float*)d_in[16];
    const float* W2    = (const float*)d_in[17];
    const float* b2    = (const float*)d_in[18];
    const float* ln2g  = (const float*)d_in[19];
    const float* ln2b  = (const float*)d_in[20];

    const int S = S_TOT, C = C_DIM;
    const long SC = (long)S * C;

    float* ws     = (float*)d_ws;
    float* tmp2   = ws;                        // SC f32 (layer output, pre-LN2)
    float* xcur   = tmp2 + SC;                 // SC f32 (LN2 out = layer input x)
    float* offraw = xcur + SC;                 // SC f32
    float* logits = offraw + SC;               // S*128 f32
    unsigned short* value_bf = (unsigned short*)(logits + (long)S * 128); // SC
    unsigned short* WT       = value_bf + SC;

    const unsigned short* WvT  = WT + 0;
    const unsigned short* WofT = WT + 393216;
    const unsigned short* WatT = WT + 786432;
    const unsigned short* WouT = WT + 983040;
    const unsigned short* W1T  = WT + 1376256;
    const unsigned short* W2T  = WT + 2949120;

    prep_weights<<<1104, 256, 0, stream>>>(Wv, Woff, Wattn, Wout, W1, W2, WT);

    for (int i = 0; i < N_LAYERS; ++i) {
        const float* Ain = (i == 0) ? src : tmp2;
        const float* g2  = (i == 0) ? nullptr : ln2g + (long)(i - 1) * C;
        const float* bb2 = (i == 0) ? nullptr : ln2b + (long)(i - 1) * C;
        const float* resWout = (i == 0) ? src : xcur;

        proj_ln<<<dim3(85, 5), 256, 0, stream>>>(
            Ain, pos, g2, bb2,
            WvT + (long)i * 65536, bv + (long)i * C,
            WofT + (long)i * 65536, boff + (long)i * 256,
            WatT + (long)i * 32768, battn + (long)i * 128,
            value_bf, offraw, logits, xcur, (i == 0) ? 0 : 1);

        layer_post<<<S / 16, 256, 0, stream>>>(
            value_bf, offraw, logits, vr, resWout,
            WouT + (long)i * 65536, bout + (long)i * C,
            ln1g + (long)i * C, ln1b + (long)i * C,
            W1T + (long)i * 262144, b1 + (long)i * F_DIM,
            W2T + (long)i * 262144, b2 + (long)i * C,
            tmp2);
    }

    ln4f<<<S / 4, 256, 0, stream>>>(
        tmp2, ln2g + (long)(N_LAYERS - 1) * C, ln2b + (long)(N_LAYERS - 1) * C,
        (float*)d_out);
}

// Round 8
// 583.315 us; speedup vs baseline: 1.3568x; 1.3568x over previous
//
#include <hip/hip_runtime.h>
#include <hip/hip_bf16.h>

#define S_TOT 5440
#define C_DIM 256
#define F_DIM 1024
#define N_LAYERS 6

__device__ __constant__ int c_HW[4]    = {64, 32, 16, 8};
__device__ __constant__ int c_logW[4]  = {6, 5, 4, 3};
__device__ __constant__ int c_start[4] = {0, 4096, 5120, 5376};

typedef __attribute__((ext_vector_type(8))) short bf16x8;
typedef __attribute__((ext_vector_type(4))) float f32x4;
typedef __attribute__((ext_vector_type(4))) unsigned int u32x4;

__device__ __forceinline__ short f2bf(float f) {
    __hip_bfloat16 h = __float2bfloat16(f);
    return *reinterpret_cast<short*>(&h);
}
union uf32 { unsigned int u; float f; };
__device__ __forceinline__ float lo_f(unsigned int u) { uf32 c; c.u = u << 16;          return c.f; }
__device__ __forceinline__ float hi_f(unsigned int u) { uf32 c; c.u = u & 0xffff0000u; return c.f; }

// ---- 16B global->LDS stage: wave-uniform LDS base + lane*16 (HW scatter) ----
__device__ __forceinline__ void gstage16(const unsigned short* g, short* ldsBase, int lane) {
#if defined(__has_builtin) && __has_builtin(__builtin_amdgcn_global_load_lds)
    __builtin_amdgcn_global_load_lds(
        (const __attribute__((address_space(1))) unsigned int*)(g),
        (__attribute__((address_space(3))) unsigned int*)(ldsBase),
        16, 0, 0);
#else
    *(bf16x8*)(ldsBase + lane * 8) = *(const bf16x8*)g;
#endif
}

// ---------------- weight prep: fp32 [K][N] -> bf16 [N][K], all 36 matrices ----------------
__global__ __launch_bounds__(256) void prep_weights(
    const float* __restrict__ Wv, const float* __restrict__ Woff,
    const float* __restrict__ Wattn, const float* __restrict__ Wout,
    const float* __restrict__ W1, const float* __restrict__ W2,
    unsigned short* __restrict__ WT)
{
    __shared__ short T[64][72];
    const int bid = blockIdx.x;
    const int layer = bid / 184;
    const int r = bid % 184;
    const float* src; unsigned short* dst; int K, N, kb, nb;
    if (r < 16)       { src = Wv    + (long)layer*65536;  dst = WT + 0       + (long)layer*65536;  K=256;  N=256;  kb=r&3;        nb=r>>2; }
    else if (r < 32)  { src = Woff  + (long)layer*65536;  dst = WT + 393216  + (long)layer*65536;  K=256;  N=256;  kb=(r-16)&3;   nb=(r-16)>>2; }
    else if (r < 40)  { src = Wattn + (long)layer*32768;  dst = WT + 786432  + (long)layer*32768;  K=256;  N=128;  kb=(r-32)&3;   nb=(r-32)>>2; }
    else if (r < 56)  { src = Wout  + (long)layer*65536;  dst = WT + 983040  + (long)layer*65536;  K=256;  N=256;  kb=(r-40)&3;   nb=(r-40)>>2; }
    else if (r < 120) { src = W1    + (long)layer*262144; dst = WT + 1376256 + (long)layer*262144; K=256;  N=1024; kb=(r-56)&3;   nb=(r-56)>>2; }
    else              { src = W2    + (long)layer*262144; dst = WT + 2949120 + (long)layer*262144; K=1024; N=256;  kb=(r-120)&15; nb=(r-120)>>4; }
    const int k0 = kb * 64, n0 = nb * 64;
    const int t = threadIdx.x;
    {
        const int row = t >> 2, cg = (t & 3) * 16;
        const float* sp = src + (long)(k0 + row) * N + n0 + cg;
        float4 v0 = *(const float4*)sp;
        float4 v1 = *(const float4*)(sp + 4);
        float4 v2 = *(const float4*)(sp + 8);
        float4 v3 = *(const float4*)(sp + 12);
        short tmp[16];
        tmp[0]=f2bf(v0.x); tmp[1]=f2bf(v0.y); tmp[2]=f2bf(v0.z); tmp[3]=f2bf(v0.w);
        tmp[4]=f2bf(v1.x); tmp[5]=f2bf(v1.y); tmp[6]=f2bf(v1.z); tmp[7]=f2bf(v1.w);
        tmp[8]=f2bf(v2.x); tmp[9]=f2bf(v2.y); tmp[10]=f2bf(v2.z); tmp[11]=f2bf(v2.w);
        tmp[12]=f2bf(v3.x); tmp[13]=f2bf(v3.y); tmp[14]=f2bf(v3.z); tmp[15]=f2bf(v3.w);
        *(bf16x8*)&T[row][cg]     = *(bf16x8*)&tmp[0];
        *(bf16x8*)&T[row][cg + 8] = *(bf16x8*)&tmp[8];
    }
    __syncthreads();
    {
        const int n = t >> 2, kg = (t & 3) * 16;
        short o[16];
        #pragma unroll
        for (int j = 0; j < 16; ++j) o[j] = T[kg + j][n];
        unsigned short* dp = dst + (long)(n0 + n) * K + k0 + kg;
        *(bf16x8*)dp       = *(bf16x8*)&o[0];
        *(bf16x8*)(dp + 8) = *(bf16x8*)&o[8];
    }
}

// ============ A-prep: load fp32 64x256 tile, optional LN, optional +pos, -> bf16 LDS ============
__device__ __forceinline__ void prep_A(
    const float* __restrict__ Ain, const float* __restrict__ g,
    const float* __restrict__ b, const float* __restrict__ pos,
    float* __restrict__ xout, int mBase, int doLN,
    short (*As)[264])
{
    const int t = threadIdx.x;
    const int row = t >> 2, q4 = t & 3;
    const long gbase = (long)(mBase + row) * 256 + q4 * 64;
    float va[64];
    #pragma unroll
    for (int j = 0; j < 16; ++j) {
        float4 v = *(const float4*)(Ain + gbase + j * 4);
        va[j*4+0] = v.x; va[j*4+1] = v.y; va[j*4+2] = v.z; va[j*4+3] = v.w;
    }
    if (doLN) {
        float s1 = 0.f, s2 = 0.f;
        #pragma unroll
        for (int j = 0; j < 64; ++j) { s1 += va[j]; s2 += va[j] * va[j]; }
        s1 += __shfl_xor(s1, 1); s2 += __shfl_xor(s2, 1);
        s1 += __shfl_xor(s1, 2); s2 += __shfl_xor(s2, 2);
        const float mean = s1 * (1.f / 256.f);
        const float var  = s2 * (1.f / 256.f) - mean * mean;
        const float rstd = rsqrtf(var + 1e-5f);
        #pragma unroll
        for (int j = 0; j < 16; ++j) {
            float4 g4 = *(const float4*)(g + q4 * 64 + j * 4);
            float4 b4 = *(const float4*)(b + q4 * 64 + j * 4);
            va[j*4+0] = (va[j*4+0] - mean) * rstd * g4.x + b4.x;
            va[j*4+1] = (va[j*4+1] - mean) * rstd * g4.y + b4.y;
            va[j*4+2] = (va[j*4+2] - mean) * rstd * g4.z + b4.z;
            va[j*4+3] = (va[j*4+3] - mean) * rstd * g4.w + b4.w;
        }
    }
    if (xout) {
        #pragma unroll
        for (int j = 0; j < 16; ++j) {
            float4 v;
            v.x = va[j*4+0]; v.y = va[j*4+1]; v.z = va[j*4+2]; v.w = va[j*4+3];
            *(float4*)(xout + gbase + j * 4) = v;
        }
    }
    if (pos) {
        #pragma unroll
        for (int j = 0; j < 16; ++j) {
            float4 p = *(const float4*)(pos + gbase + j * 4);
            va[j*4+0] += p.x; va[j*4+1] += p.y; va[j*4+2] += p.z; va[j*4+3] += p.w;
        }
    }
    #pragma unroll
    for (int j8 = 0; j8 < 8; ++j8) {
        short tmp[8];
        #pragma unroll
        for (int e = 0; e < 8; ++e) tmp[e] = f2bf(va[j8 * 8 + e]);
        *(bf16x8*)&As[row][q4 * 64 + j8 * 8] = *(bf16x8*)tmp;
    }
}

// ============ GEMM core: A resident in padded LDS (K=256), B staged via global_load_lds ============
// BsLin: NF*32 rows x 64 shorts, linear, XOR-swizzled (c16 ^= row&7 on both sides).
template<int NF>
__device__ __forceinline__ void core_Alds2(
    const unsigned short* __restrict__ Bt, int ldb, int nBase,
    const short (*As)[264], short* __restrict__ BsLin, f32x4 (&acc)[2][NF])
{
    const int t = threadIdx.x;
    const int lane = t & 63, wave = t >> 6;
    const int wr = wave >> 1, wc = wave & 1;
    const int lr = lane & 15;
    const int ldRow = lane >> 3, ldC16 = lane & 7;

    #pragma unroll
    for (int i = 0; i < 2; ++i)
        #pragma unroll
        for (int j = 0; j < NF; ++j)
            acc[i][j] = (f32x4){0.f, 0.f, 0.f, 0.f};

    for (int k0 = 0; k0 < 256; k0 += 64) {
        #pragma unroll
        for (int qq = 0; qq < NF; ++qq) {
            const int wbase = wave * (NF * 8) + qq * 8;
            const int row = wbase + ldRow;
            const int c16 = ldC16 ^ (row & 7);
            gstage16(Bt + (long)(nBase + row) * ldb + k0 + c16 * 8,
                     BsLin + wbase * 64, lane);
        }
        __syncthreads();
        #pragma unroll
        for (int kk = 0; kk < 2; ++kk) {
            const int lks = kk * 32 + (lane >> 4) * 8;
            const int c16f = lks >> 3;
            bf16x8 af[2], bfr[NF];
            #pragma unroll
            for (int fm = 0; fm < 2; ++fm)
                af[fm] = *(const bf16x8*)&As[wr * 32 + fm * 16 + lr][k0 + lks];
            #pragma unroll
            for (int fn = 0; fn < NF; ++fn) {
                const int row = wc * (NF * 16) + fn * 16 + lr;
                bfr[fn] = *(const bf16x8*)&BsLin[row * 64 + ((c16f ^ (row & 7)) << 3)];
            }
            #pragma unroll
            for (int fm = 0; fm < 2; ++fm)
                #pragma unroll
                for (int fn = 0; fn < NF; ++fn)
                    acc[fm][fn] = __builtin_amdgcn_mfma_f32_16x16x32_bf16(
                        af[fm], bfr[fn], acc[fm][fn], 0, 0, 0);
        }
        __syncthreads();
    }
}

// ============ GEMM core: A and B bf16 from global, both staged via global_load_lds ============
template<int NF>
__device__ __forceinline__ void gemm_core2(
    const unsigned short* __restrict__ A, const unsigned short* __restrict__ Bt,
    int K, int mBase, int nBase, short* __restrict__ AsLin,
    short* __restrict__ BsLin, f32x4 (&acc)[2][NF])
{
    const int t = threadIdx.x;
    const int lane = t & 63, wave = t >> 6;
    const int wr = wave >> 1, wc = wave & 1;
    const int lr = lane & 15;
    const int ldRow = lane >> 3, ldC16 = lane & 7;

    #pragma unroll
    for (int i = 0; i < 2; ++i)
        #pragma unroll
        for (int j = 0; j < NF; ++j)
            acc[i][j] = (f32x4){0.f, 0.f, 0.f, 0.f};

    for (int k0 = 0; k0 < K; k0 += 64) {
        // A: 64 rows, 2 chunks of 8 per wave
        #pragma unroll
        for (int qq = 0; qq < 2; ++qq) {
            const int wbase = wave * 16 + qq * 8;
            const int row = wbase + ldRow;
            const int c16 = ldC16 ^ (row & 7);
            gstage16(A + (long)(mBase + row) * K + k0 + c16 * 8,
                     AsLin + wbase * 64, lane);
        }
        // B: NF*32 rows
        #pragma unroll
        for (int qq = 0; qq < NF; ++qq) {
            const int wbase = wave * (NF * 8) + qq * 8;
            const int row = wbase + ldRow;
            const int c16 = ldC16 ^ (row & 7);
            gstage16(Bt + (long)(nBase + row) * K + k0 + c16 * 8,
                     BsLin + wbase * 64, lane);
        }
        __syncthreads();
        #pragma unroll
        for (int kk = 0; kk < 2; ++kk) {
            const int lks = kk * 32 + (lane >> 4) * 8;
            const int c16f = lks >> 3;
            bf16x8 af[2], bfr[NF];
            #pragma unroll
            for (int fm = 0; fm < 2; ++fm) {
                const int row = wr * 32 + fm * 16 + lr;
                af[fm] = *(const bf16x8*)&AsLin[row * 64 + ((c16f ^ (row & 7)) << 3)];
            }
            #pragma unroll
            for (int fn = 0; fn < NF; ++fn) {
                const int row = wc * (NF * 16) + fn * 16 + lr;
                bfr[fn] = *(const bf16x8*)&BsLin[row * 64 + ((c16f ^ (row & 7)) << 3)];
            }
            #pragma unroll
            for (int fm = 0; fm < 2; ++fm)
                #pragma unroll
                for (int fn = 0; fn < NF; ++fn)
                    acc[fm][fn] = __builtin_amdgcn_mfma_f32_16x16x32_bf16(
                        af[fm], bfr[fn], acc[fm][fn], 0, 0, 0);
        }
        __syncthreads();
    }
}

// ---------------- fused LN2 + projections (grid 85 x 5) ----------------
__global__ __launch_bounds__(256) void proj_ln(
    const float* __restrict__ Ain, const float* __restrict__ pos,
    const float* __restrict__ g, const float* __restrict__ b,
    const unsigned short* __restrict__ WvT, const float* __restrict__ bv,
    const unsigned short* __restrict__ WofT, const float* __restrict__ bof,
    const unsigned short* __restrict__ WatT, const float* __restrict__ bat,
    unsigned short* __restrict__ value_bf, float* __restrict__ offraw,
    float* __restrict__ logits, float* __restrict__ xcur, int doLN)
{
    __shared__ short As[64][264];
    __shared__ short BsLin[128 * 64];
    const int ny = blockIdx.y, mBase = blockIdx.x * 64;
    const unsigned short* Bp; const float* bias; int nBase, kind;
    if (ny < 2)      { Bp = WvT;  bias = bv;  nBase = ny * 128;       kind = 0; }
    else if (ny < 4) { Bp = WofT; bias = bof; nBase = (ny - 2) * 128; kind = 1; }
    else             { Bp = WatT; bias = bat; nBase = 0;              kind = 2; }

    prep_A(Ain, g, b, (kind > 0) ? pos : nullptr,
           (doLN && ny == 0) ? xcur : nullptr, mBase, doLN, As);

    f32x4 acc[2][4];
    core_Alds2<4>(Bp, 256, nBase, As, BsLin, acc);

    const int lane = threadIdx.x & 63, wave = threadIdx.x >> 6;
    const int wr = wave >> 1, wc = wave & 1;
    #pragma unroll
    for (int fm = 0; fm < 2; ++fm)
        #pragma unroll
        for (int fn = 0; fn < 4; ++fn)
            #pragma unroll
            for (int r = 0; r < 4; ++r) {
                int m = mBase + wr * 32 + fm * 16 + (lane >> 4) * 4 + r;
                int n = nBase + wc * 64 + fn * 16 + (lane & 15);
                float v = acc[fm][fn][r] + bias[n];
                if (kind == 0)      value_bf[(long)m * 256 + n] = (unsigned short)f2bf(v);
                else if (kind == 1) offraw[(long)m * 256 + n] = v;
                else                logits[(long)m * 128 + n] = v;
            }
}

// ---------------- fused LN1 + W1 GEMM + relu (grid 85 x 8) ----------------
__global__ __launch_bounds__(256) void gemm_w1ln(
    const float* __restrict__ Ain, const float* __restrict__ g,
    const float* __restrict__ b, const unsigned short* __restrict__ W1T,
    const float* __restrict__ bias, unsigned short* __restrict__ hbuf,
    float* __restrict__ xout)
{
    __shared__ short As[64][264];
    __shared__ short BsLin[128 * 64];
    const int mBase = blockIdx.x * 64, nBase = blockIdx.y * 128;

    prep_A(Ain, g, b, nullptr, (blockIdx.y == 0) ? xout : nullptr, mBase, 1, As);

    f32x4 acc[2][4];
    core_Alds2<4>(W1T, 256, nBase, As, BsLin, acc);

    const int lane = threadIdx.x & 63, wave = threadIdx.x >> 6;
    const int wr = wave >> 1, wc = wave & 1;
    #pragma unroll
    for (int fm = 0; fm < 2; ++fm)
        #pragma unroll
        for (int fn = 0; fn < 4; ++fn)
            #pragma unroll
            for (int r = 0; r < 4; ++r) {
                int m = mBase + wr * 32 + fm * 16 + (lane >> 4) * 4 + r;
                int n = nBase + wc * 64 + fn * 16 + (lane & 15);
                float v = fmaxf(acc[fm][fn][r] + bias[n], 0.f);
                hbuf[(long)m * 1024 + n] = (unsigned short)f2bf(v);
            }
}

// ---------------- plain GEMM (N=256) + bias + residual -> fp32 (grid 85 x 4) ----------------
__global__ __launch_bounds__(256) void gemm_res(
    const unsigned short* __restrict__ A, const unsigned short* __restrict__ Bt,
    const float* __restrict__ bias, const float* __restrict__ res,
    float* __restrict__ out, int K)
{
    __shared__ short AsLin[64 * 64];
    __shared__ short BsLin[64 * 64];
    const int mBase = blockIdx.x * 64, nBase = blockIdx.y * 64;
    f32x4 acc[2][2];
    gemm_core2<2>(A, Bt, K, mBase, nBase, AsLin, BsLin, acc);

    const int lane = threadIdx.x & 63, wave = threadIdx.x >> 6;
    const int wr = wave >> 1, wc = wave & 1;
    #pragma unroll
    for (int fm = 0; fm < 2; ++fm)
        #pragma unroll
        for (int fn = 0; fn < 2; ++fn)
            #pragma unroll
            for (int r = 0; r < 4; ++r) {
                int m = mBase + wr * 32 + fm * 16 + (lane >> 4) * 4 + r;
                int n = nBase + wc * 32 + fn * 16 + (lane & 15);
                out[(long)m * 256 + n] = acc[fm][fn][r] + bias[n] + res[(long)m * 256 + n];
            }
}

// ---------------- MSDA sampling v4: 2 queries/block, shfl reduce, paired bf16 extract ----------------
__global__ __launch_bounds__(256) void msda2(
    const unsigned short* __restrict__ value, const float* __restrict__ offraw,
    const float* __restrict__ logits, const float* __restrict__ vr,
    unsigned short* __restrict__ outB)
{
    const int t = threadIdx.x;
    const int q = t >> 7, tt = t & 127;
    const int s = blockIdx.x * 2 + q;

    __shared__ int4   sIdx[2][128];
    __shared__ float4 sW[2][128];

    {
        const int pt = tt & 15, l = pt >> 2;

        float lg = logits[(long)s * 128 + tt];
        float m = lg;
        #pragma unroll
        for (int o = 1; o < 16; o <<= 1) m = fmaxf(m, __shfl_xor(m, o));
        float e = expf(lg - m);
        float sum = e;
        #pragma unroll
        for (int o = 1; o < 16; o <<= 1) sum += __shfl_xor(sum, o);
        float aw = e / sum;

        int ls = (s < 4096) ? 0 : (s < 5120) ? 1 : (s < 5376) ? 2 : 3;
        int lw = c_logW[ls];
        int Wq = c_HW[ls];
        int rem = s - c_start[ls];
        int qi = rem >> lw, qj = rem & (Wq - 1);
        float xh = (qj + 0.5f) / (vr[ls * 2 + 1] * (float)Wq);
        float yh = (qi + 0.5f) / (vr[ls * 2 + 0] * (float)Wq);

        const int Wl = c_HW[l], sl = c_start[l];
        const float fW = (float)Wl;
        float refx = xh * vr[l * 2 + 1];
        float refy = yh * vr[l * 2 + 0];
        float2 oxy = *(const float2*)(offraw + (long)s * 256 + tt * 2);
        float x = refx * fW + oxy.x - 0.5f;
        float y = refy * fW + oxy.y - 0.5f;
        float x0f = floorf(x), y0f = floorf(y);
        float fx = x - x0f, fy = y - y0f;
        int x0 = (int)x0f, y0 = (int)y0f;
        int x1 = x0 + 1, y1 = y0 + 1;
        float vx0 = (x0 >= 0 && x0 < Wl) ? 1.f : 0.f;
        float vx1 = (x1 >= 0 && x1 < Wl) ? 1.f : 0.f;
        float vy0 = (y0 >= 0 && y0 < Wl) ? 1.f : 0.f;
        float vy1 = (y1 >= 0 && y1 < Wl) ? 1.f : 0.f;
        int cx0 = min(max(x0, 0), Wl - 1), cx1 = min(max(x1, 0), Wl - 1);
        int cy0 = min(max(y0, 0), Wl - 1), cy1 = min(max(y1, 0), Wl - 1);

        int4 id4;
        id4.x = sl + cy0 * Wl + cx0;
        id4.y = sl + cy0 * Wl + cx1;
        id4.z = sl + cy1 * Wl + cx0;
        id4.w = sl + cy1 * Wl + cx1;
        sIdx[q][tt] = id4;
        float4 w4;
        w4.x = aw * (1.f - fx) * (1.f - fy) * vx0 * vy0;
        w4.y = aw * fx * (1.f - fy) * vx1 * vy0;
        w4.z = aw * (1.f - fx) * fy * vx0 * vy1;
        w4.w = aw * fx * fy * vx1 * vy1;
        sW[q][tt] = w4;
    }
    __syncthreads();

    // phase 2: h = tt>>4 (8), dq = (tt>>2)&3 (channel quad), pg = tt&3 (point group)
    const int h = tt >> 4, dq = (tt >> 2) & 3, pg = tt & 3;
    const int cb = h * 32 + dq * 8;

    float a8[8] = {0.f,0.f,0.f,0.f,0.f,0.f,0.f,0.f};
    #pragma unroll
    for (int p = 0; p < 4; ++p) {
        const int ei = h * 16 + pg * 4 + p;
        int4 id = sIdx[q][ei];
        float4 w = sW[q][ei];
        u32x4 u0 = *(const u32x4*)(value + (long)id.x * 256 + cb);
        u32x4 u1 = *(const u32x4*)(value + (long)id.y * 256 + cb);
        u32x4 u2 = *(const u32x4*)(value + (long)id.z * 256 + cb);
        u32x4 u3 = *(const u32x4*)(value + (long)id.w * 256 + cb);
        #pragma unroll
        for (int j = 0; j < 4; ++j) {
            a8[2*j]   += w.x * lo_f(u0[j]) + w.y * lo_f(u1[j])
                       + w.z * lo_f(u2[j]) + w.w * lo_f(u3[j]);
            a8[2*j+1] += w.x * hi_f(u0[j]) + w.y * hi_f(u1[j])
                       + w.z * hi_f(u2[j]) + w.w * hi_f(u3[j]);
        }
    }
    // reduce over pg (lane bits 0-1, same wave)
    #pragma unroll
    for (int j = 0; j < 8; ++j) {
        a8[j] += __shfl_xor(a8[j], 1);
        a8[j] += __shfl_xor(a8[j], 2);
    }
    if (pg == 0) {
        short o8[8];
        #pragma unroll
        for (int j = 0; j < 8; ++j) o8[j] = f2bf(a8[j]);
        *(bf16x8*)(outB + (long)s * 256 + cb) = *(bf16x8*)o8;
    }
}

// ---------------- final LayerNorm: one wave per row ----------------
__global__ __launch_bounds__(256) void ln4f(
    const float* __restrict__ in, const float* __restrict__ g,
    const float* __restrict__ b, float* __restrict__ out)
{
    const int wave = threadIdx.x >> 6, lane = threadIdx.x & 63;
    const int s = blockIdx.x * 4 + wave;
    f32x4 v = *(const f32x4*)(in + (long)s * 256 + lane * 4);

    float sum = v[0] + v[1] + v[2] + v[3];
    #pragma unroll
    for (int o = 1; o < 64; o <<= 1) sum += __shfl_xor(sum, o);
    const float mean = sum * (1.f / 256.f);

    f32x4 d = v - mean;
    float sq = d[0]*d[0] + d[1]*d[1] + d[2]*d[2] + d[3]*d[3];
    #pragma unroll
    for (int o = 1; o < 64; o <<= 1) sq += __shfl_xor(sq, o);
    const float rstd = rsqrtf(sq * (1.f / 256.f) + 1e-5f);

    f32x4 gg = *(const f32x4*)(g + lane * 4);
    f32x4 bb = *(const f32x4*)(b + lane * 4);
    f32x4 o4 = d * rstd * gg + bb;
    *(f32x4*)(out + (long)s * 256 + lane * 4) = o4;
}

extern "C" void kernel_launch(void* const* d_in, const int* in_sizes, int n_in,
                              void* d_out, int out_size, void* d_ws, size_t ws_size,
                              hipStream_t stream) {
    const float* src   = (const float*)d_in[0];
    const float* pos   = (const float*)d_in[1];
    const float* vr    = (const float*)d_in[2];
    const float* Wv    = (const float*)d_in[5];
    const float* bv    = (const float*)d_in[6];
    const float* Woff  = (const float*)d_in[7];
    const float* boff  = (const float*)d_in[8];
    const float* Wattn = (const float*)d_in[9];
    const float* battn = (const float*)d_in[10];
    const float* Wout  = (const float*)d_in[11];
    const float* bout  = (const float*)d_in[12];
    const float* ln1g  = (const float*)d_in[13];
    const float* ln1b  = (const float*)d_in[14];
    const float* W1    = (const float*)d_in[15];
    const float* b1    = (const float*)d_in[16];
    const float* W2    = (const float*)d_in[17];
    const float* b2    = (const float*)d_in[18];
    const float* ln2g  = (const float*)d_in[19];
    const float* ln2b  = (const float*)d_in[20];

    const int S = S_TOT, C = C_DIM;
    const long SC = (long)S * C;

    float* ws     = (float*)d_ws;
    float* tmp2   = ws;                        // SC f32 (layer output, pre-LN2)
    float* xcur   = tmp2 + SC;                 // SC f32 (LN2 out = layer input x)
    float* offraw = xcur + SC;                 // SC f32 (aliased as xln1 after msda2)
    float* logits = offraw + SC;               // S*128 f32
    unsigned short* value_bf = (unsigned short*)(logits + (long)S * 128); // SC
    unsigned short* msda_bf  = value_bf + SC;  // SC
    unsigned short* hbuf_bf  = msda_bf + SC;   // S*F
    unsigned short* WT       = hbuf_bf + (long)S * F_DIM;

    float* xln1 = offraw;

    const unsigned short* WvT  = WT + 0;
    const unsigned short* WofT = WT + 393216;
    const unsigned short* WatT = WT + 786432;
    const unsigned short* WouT = WT + 983040;
    const unsigned short* W1T  = WT + 1376256;
    const unsigned short* W2T  = WT + 2949120;

    prep_weights<<<1104, 256, 0, stream>>>(Wv, Woff, Wattn, Wout, W1, W2, WT);

    for (int i = 0; i < N_LAYERS; ++i) {
        const float* Ain = (i == 0) ? src : tmp2;
        const float* g2  = (i == 0) ? nullptr : ln2g + (long)(i - 1) * C;
        const float* bb2 = (i == 0) ? nullptr : ln2b + (long)(i - 1) * C;
        const float* resWout = (i == 0) ? src : xcur;

        proj_ln<<<dim3(85, 5), 256, 0, stream>>>(
            Ain, pos, g2, bb2,
            WvT + (long)i * 65536, bv + (long)i * C,
            WofT + (long)i * 65536, boff + (long)i * 256,
            WatT + (long)i * 32768, battn + (long)i * 128,
            value_bf, offraw, logits, xcur, (i == 0) ? 0 : 1);

        msda2<<<S / 2, 256, 0, stream>>>(value_bf, offraw, logits, vr, msda_bf);

        gemm_res<<<dim3(85, 4), 256, 0, stream>>>(
            msda_bf, WouT + (long)i * 65536, bout + (long)i * C, resWout, tmp2, 256);

        gemm_w1ln<<<dim3(85, 8), 256, 0, stream>>>(
            tmp2, ln1g + (long)i * C, ln1b + (long)i * C,
            W1T + (long)i * 262144, b1 + (long)i * F_DIM, hbuf_bf, xln1);

        gemm_res<<<dim3(85, 4), 256, 0, stream>>>(
            hbuf_bf, W2T + (long)i * 262144, b2 + (long)i * C, xln1, tmp2, 1024);
    }

    ln4f<<<S / 4, 256, 0, stream>>>(
        tmp2, ln2g + (long)(N_LAYERS - 1) * C, ln2b + (long)(N_LAYERS - 1) * C,
        (float*)d_out);
}

// Round 9
// 580.345 us; speedup vs baseline: 1.3637x; 1.0051x over previous
//
#include <hip/hip_runtime.h>
#include <hip/hip_bf16.h>

#define S_TOT 5440
#define C_DIM 256
#define F_DIM 1024
#define N_LAYERS 6

__device__ __constant__ int c_HW[4]    = {64, 32, 16, 8};
__device__ __constant__ int c_logW[4]  = {6, 5, 4, 3};
__device__ __constant__ int c_start[4] = {0, 4096, 5120, 5376};

typedef __attribute__((ext_vector_type(8))) short bf16x8;
typedef __attribute__((ext_vector_type(4))) float f32x4;
typedef __attribute__((ext_vector_type(4))) unsigned int u32x4;

__device__ __forceinline__ short f2bf(float f) {
    __hip_bfloat16 h = __float2bfloat16(f);
    return *reinterpret_cast<short*>(&h);
}
union uf32 { unsigned int u; float f; };
__device__ __forceinline__ float lo_f(unsigned int u) { uf32 c; c.u = u << 16;          return c.f; }
__device__ __forceinline__ float hi_f(unsigned int u) { uf32 c; c.u = u & 0xffff0000u; return c.f; }

// ---------------- weight prep: fp32 [K][N] -> bf16 [N][K], all 36 matrices ----------------
__global__ __launch_bounds__(256) void prep_weights(
    const float* __restrict__ Wv, const float* __restrict__ Woff,
    const float* __restrict__ Wattn, const float* __restrict__ Wout,
    const float* __restrict__ W1, const float* __restrict__ W2,
    unsigned short* __restrict__ WT)
{
    __shared__ short T[64][72];
    const int bid = blockIdx.x;
    const int layer = bid / 184;
    const int r = bid % 184;
    const float* src; unsigned short* dst; int K, N, kb, nb;
    if (r < 16)       { src = Wv    + (long)layer*65536;  dst = WT + 0       + (long)layer*65536;  K=256;  N=256;  kb=r&3;        nb=r>>2; }
    else if (r < 32)  { src = Woff  + (long)layer*65536;  dst = WT + 393216  + (long)layer*65536;  K=256;  N=256;  kb=(r-16)&3;   nb=(r-16)>>2; }
    else if (r < 40)  { src = Wattn + (long)layer*32768;  dst = WT + 786432  + (long)layer*32768;  K=256;  N=128;  kb=(r-32)&3;   nb=(r-32)>>2; }
    else if (r < 56)  { src = Wout  + (long)layer*65536;  dst = WT + 983040  + (long)layer*65536;  K=256;  N=256;  kb=(r-40)&3;   nb=(r-40)>>2; }
    else if (r < 120) { src = W1    + (long)layer*262144; dst = WT + 1376256 + (long)layer*262144; K=256;  N=1024; kb=(r-56)&3;   nb=(r-56)>>2; }
    else              { src = W2    + (long)layer*262144; dst = WT + 2949120 + (long)layer*262144; K=1024; N=256;  kb=(r-120)&15; nb=(r-120)>>4; }
    const int k0 = kb * 64, n0 = nb * 64;
    const int t = threadIdx.x;
    {
        const int row = t >> 2, cg = (t & 3) * 16;
        const float* sp = src + (long)(k0 + row) * N + n0 + cg;
        float4 v0 = *(const float4*)sp;
        float4 v1 = *(const float4*)(sp + 4);
        float4 v2 = *(const float4*)(sp + 8);
        float4 v3 = *(const float4*)(sp + 12);
        short tmp[16];
        tmp[0]=f2bf(v0.x); tmp[1]=f2bf(v0.y); tmp[2]=f2bf(v0.z); tmp[3]=f2bf(v0.w);
        tmp[4]=f2bf(v1.x); tmp[5]=f2bf(v1.y); tmp[6]=f2bf(v1.z); tmp[7]=f2bf(v1.w);
        tmp[8]=f2bf(v2.x); tmp[9]=f2bf(v2.y); tmp[10]=f2bf(v2.z); tmp[11]=f2bf(v2.w);
        tmp[12]=f2bf(v3.x); tmp[13]=f2bf(v3.y); tmp[14]=f2bf(v3.z); tmp[15]=f2bf(v3.w);
        *(bf16x8*)&T[row][cg]     = *(bf16x8*)&tmp[0];
        *(bf16x8*)&T[row][cg + 8] = *(bf16x8*)&tmp[8];
    }
    __syncthreads();
    {
        const int n = t >> 2, kg = (t & 3) * 16;
        short o[16];
        #pragma unroll
        for (int j = 0; j < 16; ++j) o[j] = T[kg + j][n];
        unsigned short* dp = dst + (long)(n0 + n) * K + k0 + kg;
        *(bf16x8*)dp       = *(bf16x8*)&o[0];
        *(bf16x8*)(dp + 8) = *(bf16x8*)&o[8];
    }
}

// ============ A-prep: load fp32 64x256 tile, optional LN, optional +pos, -> bf16 LDS ============
__device__ __forceinline__ void prep_A(
    const float* __restrict__ Ain, const float* __restrict__ g,
    const float* __restrict__ b, const float* __restrict__ pos,
    float* __restrict__ xout, int mBase, int doLN,
    short (*As)[264])
{
    const int t = threadIdx.x;
    const int row = t >> 2, q4 = t & 3;
    const long gbase = (long)(mBase + row) * 256 + q4 * 64;
    float va[64];
    #pragma unroll
    for (int j = 0; j < 16; ++j) {
        float4 v = *(const float4*)(Ain + gbase + j * 4);
        va[j*4+0] = v.x; va[j*4+1] = v.y; va[j*4+2] = v.z; va[j*4+3] = v.w;
    }
    if (doLN) {
        float s1 = 0.f, s2 = 0.f;
        #pragma unroll
        for (int j = 0; j < 64; ++j) { s1 += va[j]; s2 += va[j] * va[j]; }
        s1 += __shfl_xor(s1, 1); s2 += __shfl_xor(s2, 1);
        s1 += __shfl_xor(s1, 2); s2 += __shfl_xor(s2, 2);
        const float mean = s1 * (1.f / 256.f);
        const float var  = s2 * (1.f / 256.f) - mean * mean;
        const float rstd = rsqrtf(var + 1e-5f);
        #pragma unroll
        for (int j = 0; j < 16; ++j) {
            float4 g4 = *(const float4*)(g + q4 * 64 + j * 4);
            float4 b4 = *(const float4*)(b + q4 * 64 + j * 4);
            va[j*4+0] = (va[j*4+0] - mean) * rstd * g4.x + b4.x;
            va[j*4+1] = (va[j*4+1] - mean) * rstd * g4.y + b4.y;
            va[j*4+2] = (va[j*4+2] - mean) * rstd * g4.z + b4.z;
            va[j*4+3] = (va[j*4+3] - mean) * rstd * g4.w + b4.w;
        }
    }
    if (xout) {
        #pragma unroll
        for (int j = 0; j < 16; ++j) {
            float4 v;
            v.x = va[j*4+0]; v.y = va[j*4+1]; v.z = va[j*4+2]; v.w = va[j*4+3];
            *(float4*)(xout + gbase + j * 4) = v;
        }
    }
    if (pos) {
        #pragma unroll
        for (int j = 0; j < 16; ++j) {
            float4 p = *(const float4*)(pos + gbase + j * 4);
            va[j*4+0] += p.x; va[j*4+1] += p.y; va[j*4+2] += p.z; va[j*4+3] += p.w;
        }
    }
    #pragma unroll
    for (int j8 = 0; j8 < 8; ++j8) {
        short tmp[8];
        #pragma unroll
        for (int e = 0; e < 8; ++e) tmp[e] = f2bf(va[j8 * 8 + e]);
        *(bf16x8*)&As[row][q4 * 64 + j8 * 8] = *(bf16x8*)tmp;
    }
}

// ============ GEMM core with A resident in LDS (K=256), B streamed ============
template<int NF>
__device__ __forceinline__ void core_Alds(
    const unsigned short* __restrict__ Bt, int nBase,
    const short (*As)[264], short (*Bs)[72], f32x4 (&acc)[2][NF])
{
    const int t = threadIdx.x;
    const int lane = t & 63, wave = t >> 6;
    const int wr = wave >> 1, wc = wave & 1;
    const int lr = lane & 15;

    #pragma unroll
    for (int i = 0; i < 2; ++i)
        #pragma unroll
        for (int j = 0; j < NF; ++j)
            acc[i][j] = (f32x4){0.f, 0.f, 0.f, 0.f};

    for (int k0 = 0; k0 < 256; k0 += 64) {
        bf16x8 rb[NF];
        #pragma unroll
        for (int q = 0; q < NF; ++q) {
            int flat = q * 256 + t, row = flat >> 3, cg = (flat & 7) * 8;
            rb[q] = *(const bf16x8*)(Bt + (long)(nBase + row) * 256 + k0 + cg);
        }
        __syncthreads();
        #pragma unroll
        for (int q = 0; q < NF; ++q) {
            int flat = q * 256 + t, row = flat >> 3, cg = (flat & 7) * 8;
            *(bf16x8*)&Bs[row][cg] = rb[q];
        }
        __syncthreads();
        #pragma unroll
        for (int kk = 0; kk < 2; ++kk) {
            const int lks = kk * 32 + (lane >> 4) * 8;
            bf16x8 af[2], bfr[NF];
            #pragma unroll
            for (int fm = 0; fm < 2; ++fm)
                af[fm] = *(const bf16x8*)&As[wr * 32 + fm * 16 + lr][k0 + lks];
            #pragma unroll
            for (int fn = 0; fn < NF; ++fn)
                bfr[fn] = *(bf16x8*)&Bs[wc * (NF * 16) + fn * 16 + lr][lks];
            #pragma unroll
            for (int fm = 0; fm < 2; ++fm)
                #pragma unroll
                for (int fn = 0; fn < NF; ++fn)
                    acc[fm][fn] = __builtin_amdgcn_mfma_f32_16x16x32_bf16(
                        af[fm], bfr[fn], acc[fm][fn], 0, 0, 0);
        }
    }
}

// ============ GEMM core with bf16 A from global (round-4 proven) ============
template<int NF>
__device__ __forceinline__ void gemm_core(
    const unsigned short* __restrict__ A, const unsigned short* __restrict__ Bt,
    int K, int mBase, int nBase, short (*As)[72], short (*Bs)[72],
    f32x4 (&acc)[2][NF])
{
    const int t = threadIdx.x;
    const int lane = t & 63, wave = t >> 6;
    const int wr = wave >> 1, wc = wave & 1;
    const int lr = lane & 15;

    #pragma unroll
    for (int i = 0; i < 2; ++i)
        #pragma unroll
        for (int j = 0; j < NF; ++j)
            acc[i][j] = (f32x4){0.f, 0.f, 0.f, 0.f};

    for (int k0 = 0; k0 < K; k0 += 64) {
        bf16x8 ra[2], rb[NF];
        #pragma unroll
        for (int q = 0; q < 2; ++q) {
            int flat = q * 256 + t, row = flat >> 3, cg = (flat & 7) * 8;
            ra[q] = *(const bf16x8*)(A + (long)(mBase + row) * K + k0 + cg);
        }
        #pragma unroll
        for (int q = 0; q < NF; ++q) {
            int flat = q * 256 + t, row = flat >> 3, cg = (flat & 7) * 8;
            rb[q] = *(const bf16x8*)(Bt + (long)(nBase + row) * K + k0 + cg);
        }
        __syncthreads();
        #pragma unroll
        for (int q = 0; q < 2; ++q) {
            int flat = q * 256 + t, row = flat >> 3, cg = (flat & 7) * 8;
            *(bf16x8*)&As[row][cg] = ra[q];
        }
        #pragma unroll
        for (int q = 0; q < NF; ++q) {
            int flat = q * 256 + t, row = flat >> 3, cg = (flat & 7) * 8;
            *(bf16x8*)&Bs[row][cg] = rb[q];
        }
        __syncthreads();
        #pragma unroll
        for (int kk = 0; kk < 2; ++kk) {
            const int lks = kk * 32 + (lane >> 4) * 8;
            bf16x8 af[2], bfr[NF];
            #pragma unroll
            for (int fm = 0; fm < 2; ++fm)
                af[fm] = *(bf16x8*)&As[wr * 32 + fm * 16 + lr][lks];
            #pragma unroll
            for (int fn = 0; fn < NF; ++fn)
                bfr[fn] = *(bf16x8*)&Bs[wc * (NF * 16) + fn * 16 + lr][lks];
            #pragma unroll
            for (int fm = 0; fm < 2; ++fm)
                #pragma unroll
                for (int fn = 0; fn < NF; ++fn)
                    acc[fm][fn] = __builtin_amdgcn_mfma_f32_16x16x32_bf16(
                        af[fm], bfr[fn], acc[fm][fn], 0, 0, 0);
        }
    }
}

// ---------------- fused LN2 + projections (grid 85 x 5) ----------------
__global__ __launch_bounds__(256) void proj_ln(
    const float* __restrict__ Ain, const float* __restrict__ pos,
    const float* __restrict__ g, const float* __restrict__ b,
    const unsigned short* __restrict__ WvT, const float* __restrict__ bv,
    const unsigned short* __restrict__ WofT, const float* __restrict__ bof,
    const unsigned short* __restrict__ WatT, const float* __restrict__ bat,
    unsigned short* __restrict__ value_bf, float* __restrict__ offraw,
    float* __restrict__ logits, float* __restrict__ xcur, int doLN)
{
    __shared__ short As[64][264];
    __shared__ short Bs[128][72];
    const int ny = blockIdx.y, mBase = blockIdx.x * 64;
    const unsigned short* Bp; const float* bias; int nBase, kind;
    if (ny < 2)      { Bp = WvT;  bias = bv;  nBase = ny * 128;       kind = 0; }
    else if (ny < 4) { Bp = WofT; bias = bof; nBase = (ny - 2) * 128; kind = 1; }
    else             { Bp = WatT; bias = bat; nBase = 0;              kind = 2; }

    prep_A(Ain, g, b, (kind > 0) ? pos : nullptr,
           (doLN && ny == 0) ? xcur : nullptr, mBase, doLN, As);

    f32x4 acc[2][4];
    core_Alds<4>(Bp, nBase, As, Bs, acc);

    const int lane = threadIdx.x & 63, wave = threadIdx.x >> 6;
    const int wr = wave >> 1, wc = wave & 1;
    #pragma unroll
    for (int fm = 0; fm < 2; ++fm)
        #pragma unroll
        for (int fn = 0; fn < 4; ++fn)
            #pragma unroll
            for (int r = 0; r < 4; ++r) {
                int m = mBase + wr * 32 + fm * 16 + (lane >> 4) * 4 + r;
                int n = nBase + wc * 64 + fn * 16 + (lane & 15);
                float v = acc[fm][fn][r] + bias[n];
                if (kind == 0)      value_bf[(long)m * 256 + n] = (unsigned short)f2bf(v);
                else if (kind == 1) offraw[(long)m * 256 + n] = v;
                else                logits[(long)m * 128 + n] = v;
            }
}

// ---------------- fused LN1 + W1 GEMM + relu (grid 85 x 8) ----------------
__global__ __launch_bounds__(256) void gemm_w1ln(
    const float* __restrict__ Ain, const float* __restrict__ g,
    const float* __restrict__ b, const unsigned short* __restrict__ W1T,
    const float* __restrict__ bias, unsigned short* __restrict__ hbuf,
    float* __restrict__ xout)
{
    __shared__ short As[64][264];
    __shared__ short Bs[128][72];
    const int mBase = blockIdx.x * 64, nBase = blockIdx.y * 128;

    prep_A(Ain, g, b, nullptr, (blockIdx.y == 0) ? xout : nullptr, mBase, 1, As);

    f32x4 acc[2][4];
    core_Alds<4>(W1T, nBase, As, Bs, acc);

    const int lane = threadIdx.x & 63, wave = threadIdx.x >> 6;
    const int wr = wave >> 1, wc = wave & 1;
    #pragma unroll
    for (int fm = 0; fm < 2; ++fm)
        #pragma unroll
        for (int fn = 0; fn < 4; ++fn)
            #pragma unroll
            for (int r = 0; r < 4; ++r) {
                int m = mBase + wr * 32 + fm * 16 + (lane >> 4) * 4 + r;
                int n = nBase + wc * 64 + fn * 16 + (lane & 15);
                float v = fmaxf(acc[fm][fn][r] + bias[n], 0.f);
                hbuf[(long)m * 1024 + n] = (unsigned short)f2bf(v);
            }
}

// ---------------- plain GEMM (N=256) + bias + residual -> fp32 (grid 85 x 4) ----------------
__global__ __launch_bounds__(256) void gemm_res(
    const unsigned short* __restrict__ A, const unsigned short* __restrict__ Bt,
    const float* __restrict__ bias, const float* __restrict__ res,
    float* __restrict__ out, int K)
{
    __shared__ short As[64][72];
    __shared__ short Bs[64][72];
    const int mBase = blockIdx.x * 64, nBase = blockIdx.y * 64;
    f32x4 acc[2][2];
    gemm_core<2>(A, Bt, K, mBase, nBase, As, Bs, acc);

    const int lane = threadIdx.x & 63, wave = threadIdx.x >> 6;
    const int wr = wave >> 1, wc = wave & 1;
    #pragma unroll
    for (int fm = 0; fm < 2; ++fm)
        #pragma unroll
        for (int fn = 0; fn < 2; ++fn)
            #pragma unroll
            for (int r = 0; r < 4; ++r) {
                int m = mBase + wr * 32 + fm * 16 + (lane >> 4) * 4 + r;
                int n = nBase + wc * 32 + fn * 16 + (lane & 15);
                out[(long)m * 256 + n] = acc[fm][fn][r] + bias[n] + res[(long)m * 256 + n];
            }
}

// ---------------- MSDA sampling v4: 2 queries/block, shfl reduce, paired bf16 extract ----------------
__global__ __launch_bounds__(256) void msda2(
    const unsigned short* __restrict__ value, const float* __restrict__ offraw,
    const float* __restrict__ logits, const float* __restrict__ vr,
    unsigned short* __restrict__ outB)
{
    const int t = threadIdx.x;
    const int q = t >> 7, tt = t & 127;
    const int s = blockIdx.x * 2 + q;

    __shared__ int4   sIdx[2][128];
    __shared__ float4 sW[2][128];

    {
        const int pt = tt & 15, l = pt >> 2;

        float lg = logits[(long)s * 128 + tt];
        float m = lg;
        #pragma unroll
        for (int o = 1; o < 16; o <<= 1) m = fmaxf(m, __shfl_xor(m, o));
        float e = expf(lg - m);
        float sum = e;
        #pragma unroll
        for (int o = 1; o < 16; o <<= 1) sum += __shfl_xor(sum, o);
        float aw = e / sum;

        int ls = (s < 4096) ? 0 : (s < 5120) ? 1 : (s < 5376) ? 2 : 3;
        int lw = c_logW[ls];
        int Wq = c_HW[ls];
        int rem = s - c_start[ls];
        int qi = rem >> lw, qj = rem & (Wq - 1);
        float xh = (qj + 0.5f) / (vr[ls * 2 + 1] * (float)Wq);
        float yh = (qi + 0.5f) / (vr[ls * 2 + 0] * (float)Wq);

        const int Wl = c_HW[l], sl = c_start[l];
        const float fW = (float)Wl;
        float refx = xh * vr[l * 2 + 1];
        float refy = yh * vr[l * 2 + 0];
        float2 oxy = *(const float2*)(offraw + (long)s * 256 + tt * 2);
        float x = refx * fW + oxy.x - 0.5f;
        float y = refy * fW + oxy.y - 0.5f;
        float x0f = floorf(x), y0f = floorf(y);
        float fx = x - x0f, fy = y - y0f;
        int x0 = (int)x0f, y0 = (int)y0f;
        int x1 = x0 + 1, y1 = y0 + 1;
        float vx0 = (x0 >= 0 && x0 < Wl) ? 1.f : 0.f;
        float vx1 = (x1 >= 0 && x1 < Wl) ? 1.f : 0.f;
        float vy0 = (y0 >= 0 && y0 < Wl) ? 1.f : 0.f;
        float vy1 = (y1 >= 0 && y1 < Wl) ? 1.f : 0.f;
        int cx0 = min(max(x0, 0), Wl - 1), cx1 = min(max(x1, 0), Wl - 1);
        int cy0 = min(max(y0, 0), Wl - 1), cy1 = min(max(y1, 0), Wl - 1);

        int4 id4;
        id4.x = sl + cy0 * Wl + cx0;
        id4.y = sl + cy0 * Wl + cx1;
        id4.z = sl + cy1 * Wl + cx0;
        id4.w = sl + cy1 * Wl + cx1;
        sIdx[q][tt] = id4;
        float4 w4;
        w4.x = aw * (1.f - fx) * (1.f - fy) * vx0 * vy0;
        w4.y = aw * fx * (1.f - fy) * vx1 * vy0;
        w4.z = aw * (1.f - fx) * fy * vx0 * vy1;
        w4.w = aw * fx * fy * vx1 * vy1;
        sW[q][tt] = w4;
    }
    __syncthreads();

    // phase 2: h = tt>>4 (8 heads), dq = (tt>>2)&3 (channel quad of 8), pg = tt&3 (point group)
    const int h = tt >> 4, dq = (tt >> 2) & 3, pg = tt & 3;
    const int cb = h * 32 + dq * 8;

    float a8[8] = {0.f,0.f,0.f,0.f,0.f,0.f,0.f,0.f};
    #pragma unroll
    for (int p = 0; p < 4; ++p) {
        const int ei = h * 16 + pg * 4 + p;
        int4 id = sIdx[q][ei];
        float4 w = sW[q][ei];
        u32x4 u0 = *(const u32x4*)(value + (long)id.x * 256 + cb);
        u32x4 u1 = *(const u32x4*)(value + (long)id.y * 256 + cb);
        u32x4 u2 = *(const u32x4*)(value + (long)id.z * 256 + cb);
        u32x4 u3 = *(const u32x4*)(value + (long)id.w * 256 + cb);
        #pragma unroll
        for (int j = 0; j < 4; ++j) {
            a8[2*j]   += w.x * lo_f(u0[j]) + w.y * lo_f(u1[j])
                       + w.z * lo_f(u2[j]) + w.w * lo_f(u3[j]);
            a8[2*j+1] += w.x * hi_f(u0[j]) + w.y * hi_f(u1[j])
                       + w.z * hi_f(u2[j]) + w.w * hi_f(u3[j]);
        }
    }
    // reduce over pg (lane bits 0-1, same wave)
    #pragma unroll
    for (int j = 0; j < 8; ++j) {
        a8[j] += __shfl_xor(a8[j], 1);
        a8[j] += __shfl_xor(a8[j], 2);
    }
    if (pg == 0) {
        short o8[8];
        #pragma unroll
        for (int j = 0; j < 8; ++j) o8[j] = f2bf(a8[j]);
        *(bf16x8*)(outB + (long)s * 256 + cb) = *(bf16x8*)o8;
    }
}

// ---------------- final LayerNorm: one wave per row ----------------
__global__ __launch_bounds__(256) void ln4f(
    const float* __restrict__ in, const float* __restrict__ g,
    const float* __restrict__ b, float* __restrict__ out)
{
    const int wave = threadIdx.x >> 6, lane = threadIdx.x & 63;
    const int s = blockIdx.x * 4 + wave;
    f32x4 v = *(const f32x4*)(in + (long)s * 256 + lane * 4);

    float sum = v[0] + v[1] + v[2] + v[3];
    #pragma unroll
    for (int o = 1; o < 64; o <<= 1) sum += __shfl_xor(sum, o);
    const float mean = sum * (1.f / 256.f);

    f32x4 d = v - mean;
    float sq = d[0]*d[0] + d[1]*d[1] + d[2]*d[2] + d[3]*d[3];
    #pragma unroll
    for (int o = 1; o < 64; o <<= 1) sq += __shfl_xor(sq, o);
    const float rstd = rsqrtf(sq * (1.f / 256.f) + 1e-5f);

    f32x4 gg = *(const f32x4*)(g + lane * 4);
    f32x4 bb = *(const f32x4*)(b + lane * 4);
    f32x4 o4 = d * rstd * gg + bb;
    *(f32x4*)(out + (long)s * 256 + lane * 4) = o4;
}

extern "C" void kernel_launch(void* const* d_in, const int* in_sizes, int n_in,
                              void* d_out, int out_size, void* d_ws, size_t ws_size,
                              hipStream_t stream) {
    const float* src   = (const float*)d_in[0];
    const float* pos   = (const float*)d_in[1];
    const float* vr    = (const float*)d_in[2];
    const float* Wv    = (const float*)d_in[5];
    const float* bv    = (const float*)d_in[6];
    const float* Woff  = (const float*)d_in[7];
    const float* boff  = (const float*)d_in[8];
    const float* Wattn = (const float*)d_in[9];
    const float* battn = (const float*)d_in[10];
    const float* Wout  = (const float*)d_in[11];
    const float* bout  = (const float*)d_in[12];
    const float* ln1g  = (const float*)d_in[13];
    const float* ln1b  = (const float*)d_in[14];
    const float* W1    = (const float*)d_in[15];
    const float* b1    = (const float*)d_in[16];
    const float* W2    = (const float*)d_in[17];
    const float* b2    = (const float*)d_in[18];
    const float* ln2g  = (const float*)d_in[19];
    const float* ln2b  = (const float*)d_in[20];

    const int S = S_TOT, C = C_DIM;
    const long SC = (long)S * C;

    float* ws     = (float*)d_ws;
    float* tmp2   = ws;                        // SC f32 (layer output, pre-LN2)
    float* xcur   = tmp2 + SC;                 // SC f32 (LN2 out = layer input x)
    float* offraw = xcur + SC;                 // SC f32 (aliased as xln1 after msda2)
    float* logits = offraw + SC;               // S*128 f32
    unsigned short* value_bf = (unsigned short*)(logits + (long)S * 128); // SC
    unsigned short* msda_bf  = value_bf + SC;  // SC
    unsigned short* hbuf_bf  = msda_bf + SC;   // S*F
    unsigned short* WT       = hbuf_bf + (long)S * F_DIM;

    float* xln1 = offraw;

    const unsigned short* WvT  = WT + 0;
    const unsigned short* WofT = WT + 393216;
    const unsigned short* WatT = WT + 786432;
    const unsigned short* WouT = WT + 983040;
    const unsigned short* W1T  = WT + 1376256;
    const unsigned short* W2T  = WT + 2949120;

    prep_weights<<<1104, 256, 0, stream>>>(Wv, Woff, Wattn, Wout, W1, W2, WT);

    for (int i = 0; i < N_LAYERS; ++i) {
        const float* Ain = (i == 0) ? src : tmp2;
        const float* g2  = (i == 0) ? nullptr : ln2g + (long)(i - 1) * C;
        const float* bb2 = (i == 0) ? nullptr : ln2b + (long)(i - 1) * C;
        const float* resWout = (i == 0) ? src : xcur;

        proj_ln<<<dim3(85, 5), 256, 0, stream>>>(
            Ain, pos, g2, bb2,
            WvT + (long)i * 65536, bv + (long)i * C,
            WofT + (long)i * 65536, boff + (long)i * 256,
            WatT + (long)i * 32768, battn + (long)i * 128,
            value_bf, offraw, logits, xcur, (i == 0) ? 0 : 1);

        msda2<<<S / 2, 256, 0, stream>>>(value_bf, offraw, logits, vr, msda_bf);

        gemm_res<<<dim3(85, 4), 256, 0, stream>>>(
            msda_bf, WouT + (long)i * 65536, bout + (long)i * C, resWout, tmp2, 256);

        gemm_w1ln<<<dim3(85, 8), 256, 0, stream>>>(
            tmp2, ln1g + (long)i * C, ln1b + (long)i * C,
            W1T + (long)i * 262144, b1 + (long)i * F_DIM, hbuf_bf, xln1);

        gemm_res<<<dim3(85, 4), 256, 0, stream>>>(
            hbuf_bf, W2T + (long)i * 262144, b2 + (long)i * C, xln1, tmp2, 1024);
    }

    ln4f<<<S / 4, 256, 0, stream>>>(
        tmp2, ln2g + (long)(N_LAYERS - 1) * C, ln2b + (long)(N_LAYERS - 1) * C,
        (float*)d_out);
}

// Round 10
// 503.516 us; speedup vs baseline: 1.5718x; 1.1526x over previous
//
#include <hip/hip_runtime.h>
#include <hip/hip_bf16.h>

#define S_TOT 5440
#define C_DIM 256
#define F_DIM 1024
#define N_LAYERS 6

__device__ __constant__ int c_HW[4]    = {64, 32, 16, 8};
__device__ __constant__ int c_logW[4]  = {6, 5, 4, 3};
__device__ __constant__ int c_start[4] = {0, 4096, 5120, 5376};

typedef __attribute__((ext_vector_type(8))) short bf16x8;
typedef __attribute__((ext_vector_type(4))) float f32x4;
typedef __attribute__((ext_vector_type(4))) unsigned int u32x4;

__device__ __forceinline__ short f2bf(float f) {
    __hip_bfloat16 h = __float2bfloat16(f);
    return *reinterpret_cast<short*>(&h);
}
union uf32 { unsigned int u; float f; };
__device__ __forceinline__ float lo_f(unsigned int u) { uf32 c; c.u = u << 16;          return c.f; }
__device__ __forceinline__ float hi_f(unsigned int u) { uf32 c; c.u = u & 0xffff0000u; return c.f; }

// ---------------- weight prep: fp32 [K][N] -> bf16 [N][K], all 36 matrices ----------------
__global__ __launch_bounds__(256) void prep_weights(
    const float* __restrict__ Wv, const float* __restrict__ Woff,
    const float* __restrict__ Wattn, const float* __restrict__ Wout,
    const float* __restrict__ W1, const float* __restrict__ W2,
    unsigned short* __restrict__ WT)
{
    __shared__ short T[64][72];
    const int bid = blockIdx.x;
    const int layer = bid / 184;
    const int r = bid % 184;
    const float* src; unsigned short* dst; int K, N, kb, nb;
    if (r < 16)       { src = Wv    + (long)layer*65536;  dst = WT + 0       + (long)layer*65536;  K=256;  N=256;  kb=r&3;        nb=r>>2; }
    else if (r < 32)  { src = Woff  + (long)layer*65536;  dst = WT + 393216  + (long)layer*65536;  K=256;  N=256;  kb=(r-16)&3;   nb=(r-16)>>2; }
    else if (r < 40)  { src = Wattn + (long)layer*32768;  dst = WT + 786432  + (long)layer*32768;  K=256;  N=128;  kb=(r-32)&3;   nb=(r-32)>>2; }
    else if (r < 56)  { src = Wout  + (long)layer*65536;  dst = WT + 983040  + (long)layer*65536;  K=256;  N=256;  kb=(r-40)&3;   nb=(r-40)>>2; }
    else if (r < 120) { src = W1    + (long)layer*262144; dst = WT + 1376256 + (long)layer*262144; K=256;  N=1024; kb=(r-56)&3;   nb=(r-56)>>2; }
    else              { src = W2    + (long)layer*262144; dst = WT + 2949120 + (long)layer*262144; K=1024; N=256;  kb=(r-120)&15; nb=(r-120)>>4; }
    const int k0 = kb * 64, n0 = nb * 64;
    const int t = threadIdx.x;
    {
        const int row = t >> 2, cg = (t & 3) * 16;
        const float* sp = src + (long)(k0 + row) * N + n0 + cg;
        float4 v0 = *(const float4*)sp;
        float4 v1 = *(const float4*)(sp + 4);
        float4 v2 = *(const float4*)(sp + 8);
        float4 v3 = *(const float4*)(sp + 12);
        short tmp[16];
        tmp[0]=f2bf(v0.x); tmp[1]=f2bf(v0.y); tmp[2]=f2bf(v0.z); tmp[3]=f2bf(v0.w);
        tmp[4]=f2bf(v1.x); tmp[5]=f2bf(v1.y); tmp[6]=f2bf(v1.z); tmp[7]=f2bf(v1.w);
        tmp[8]=f2bf(v2.x); tmp[9]=f2bf(v2.y); tmp[10]=f2bf(v2.z); tmp[11]=f2bf(v2.w);
        tmp[12]=f2bf(v3.x); tmp[13]=f2bf(v3.y); tmp[14]=f2bf(v3.z); tmp[15]=f2bf(v3.w);
        *(bf16x8*)&T[row][cg]     = *(bf16x8*)&tmp[0];
        *(bf16x8*)&T[row][cg + 8] = *(bf16x8*)&tmp[8];
    }
    __syncthreads();
    {
        const int n = t >> 2, kg = (t & 3) * 16;
        short o[16];
        #pragma unroll
        for (int j = 0; j < 16; ++j) o[j] = T[kg + j][n];
        unsigned short* dp = dst + (long)(n0 + n) * K + k0 + kg;
        *(bf16x8*)dp       = *(bf16x8*)&o[0];
        *(bf16x8*)(dp + 8) = *(bf16x8*)&o[8];
    }
}

// ============ A-prep: load fp32 64x256 tile, optional LN, optional +pos, -> bf16 LDS ============
__device__ __forceinline__ void prep_A(
    const float* __restrict__ Ain, const float* __restrict__ g,
    const float* __restrict__ b, const float* __restrict__ pos,
    float* __restrict__ xout, int mBase, int doLN,
    short (*As)[264])
{
    const int t = threadIdx.x;
    const int row = t >> 2, q4 = t & 3;
    const long gbase = (long)(mBase + row) * 256 + q4 * 64;
    float va[64];
    #pragma unroll
    for (int j = 0; j < 16; ++j) {
        float4 v = *(const float4*)(Ain + gbase + j * 4);
        va[j*4+0] = v.x; va[j*4+1] = v.y; va[j*4+2] = v.z; va[j*4+3] = v.w;
    }
    if (doLN) {
        float s1 = 0.f, s2 = 0.f;
        #pragma unroll
        for (int j = 0; j < 64; ++j) { s1 += va[j]; s2 += va[j] * va[j]; }
        s1 += __shfl_xor(s1, 1); s2 += __shfl_xor(s2, 1);
        s1 += __shfl_xor(s1, 2); s2 += __shfl_xor(s2, 2);
        const float mean = s1 * (1.f / 256.f);
        const float var  = s2 * (1.f / 256.f) - mean * mean;
        const float rstd = rsqrtf(var + 1e-5f);
        #pragma unroll
        for (int j = 0; j < 16; ++j) {
            float4 g4 = *(const float4*)(g + q4 * 64 + j * 4);
            float4 b4 = *(const float4*)(b + q4 * 64 + j * 4);
            va[j*4+0] = (va[j*4+0] - mean) * rstd * g4.x + b4.x;
            va[j*4+1] = (va[j*4+1] - mean) * rstd * g4.y + b4.y;
            va[j*4+2] = (va[j*4+2] - mean) * rstd * g4.z + b4.z;
            va[j*4+3] = (va[j*4+3] - mean) * rstd * g4.w + b4.w;
        }
    }
    if (xout) {
        #pragma unroll
        for (int j = 0; j < 16; ++j) {
            float4 v;
            v.x = va[j*4+0]; v.y = va[j*4+1]; v.z = va[j*4+2]; v.w = va[j*4+3];
            *(float4*)(xout + gbase + j * 4) = v;
        }
    }
    if (pos) {
        #pragma unroll
        for (int j = 0; j < 16; ++j) {
            float4 p = *(const float4*)(pos + gbase + j * 4);
            va[j*4+0] += p.x; va[j*4+1] += p.y; va[j*4+2] += p.z; va[j*4+3] += p.w;
        }
    }
    #pragma unroll
    for (int j8 = 0; j8 < 8; ++j8) {
        short tmp[8];
        #pragma unroll
        for (int e = 0; e < 8; ++e) tmp[e] = f2bf(va[j8 * 8 + e]);
        *(bf16x8*)&As[row][q4 * 64 + j8 * 8] = *(bf16x8*)tmp;
    }
}

// ============ GEMM core with A resident in LDS (K=256), B streamed ============
template<int NF>
__device__ __forceinline__ void core_Alds(
    const unsigned short* __restrict__ Bt, int nBase,
    const short (*As)[264], short (*Bs)[72], f32x4 (&acc)[2][NF])
{
    const int t = threadIdx.x;
    const int lane = t & 63, wave = t >> 6;
    const int wr = wave >> 1, wc = wave & 1;
    const int lr = lane & 15;

    #pragma unroll
    for (int i = 0; i < 2; ++i)
        #pragma unroll
        for (int j = 0; j < NF; ++j)
            acc[i][j] = (f32x4){0.f, 0.f, 0.f, 0.f};

    for (int k0 = 0; k0 < 256; k0 += 64) {
        bf16x8 rb[NF];
        #pragma unroll
        for (int q = 0; q < NF; ++q) {
            int flat = q * 256 + t, row = flat >> 3, cg = (flat & 7) * 8;
            rb[q] = *(const bf16x8*)(Bt + (long)(nBase + row) * 256 + k0 + cg);
        }
        __syncthreads();
        #pragma unroll
        for (int q = 0; q < NF; ++q) {
            int flat = q * 256 + t, row = flat >> 3, cg = (flat & 7) * 8;
            *(bf16x8*)&Bs[row][cg] = rb[q];
        }
        __syncthreads();
        #pragma unroll
        for (int kk = 0; kk < 2; ++kk) {
            const int lks = kk * 32 + (lane >> 4) * 8;
            bf16x8 af[2], bfr[NF];
            #pragma unroll
            for (int fm = 0; fm < 2; ++fm)
                af[fm] = *(const bf16x8*)&As[wr * 32 + fm * 16 + lr][k0 + lks];
            #pragma unroll
            for (int fn = 0; fn < NF; ++fn)
                bfr[fn] = *(bf16x8*)&Bs[wc * (NF * 16) + fn * 16 + lr][lks];
            #pragma unroll
            for (int fm = 0; fm < 2; ++fm)
                #pragma unroll
                for (int fn = 0; fn < NF; ++fn)
                    acc[fm][fn] = __builtin_amdgcn_mfma_f32_16x16x32_bf16(
                        af[fm], bfr[fn], acc[fm][fn], 0, 0, 0);
        }
    }
}

// ============ GEMM core with bf16 A from global (round-4 proven) ============
template<int NF>
__device__ __forceinline__ void gemm_core(
    const unsigned short* __restrict__ A, const unsigned short* __restrict__ Bt,
    int K, int mBase, int nBase, short (*As)[72], short (*Bs)[72],
    f32x4 (&acc)[2][NF])
{
    const int t = threadIdx.x;
    const int lane = t & 63, wave = t >> 6;
    const int wr = wave >> 1, wc = wave & 1;
    const int lr = lane & 15;

    #pragma unroll
    for (int i = 0; i < 2; ++i)
        #pragma unroll
        for (int j = 0; j < NF; ++j)
            acc[i][j] = (f32x4){0.f, 0.f, 0.f, 0.f};

    for (int k0 = 0; k0 < K; k0 += 64) {
        bf16x8 ra[2], rb[NF];
        #pragma unroll
        for (int q = 0; q < 2; ++q) {
            int flat = q * 256 + t, row = flat >> 3, cg = (flat & 7) * 8;
            ra[q] = *(const bf16x8*)(A + (long)(mBase + row) * K + k0 + cg);
        }
        #pragma unroll
        for (int q = 0; q < NF; ++q) {
            int flat = q * 256 + t, row = flat >> 3, cg = (flat & 7) * 8;
            rb[q] = *(const bf16x8*)(Bt + (long)(nBase + row) * K + k0 + cg);
        }
        __syncthreads();
        #pragma unroll
        for (int q = 0; q < 2; ++q) {
            int flat = q * 256 + t, row = flat >> 3, cg = (flat & 7) * 8;
            *(bf16x8*)&As[row][cg] = ra[q];
        }
        #pragma unroll
        for (int q = 0; q < NF; ++q) {
            int flat = q * 256 + t, row = flat >> 3, cg = (flat & 7) * 8;
            *(bf16x8*)&Bs[row][cg] = rb[q];
        }
        __syncthreads();
        #pragma unroll
        for (int kk = 0; kk < 2; ++kk) {
            const int lks = kk * 32 + (lane >> 4) * 8;
            bf16x8 af[2], bfr[NF];
            #pragma unroll
            for (int fm = 0; fm < 2; ++fm)
                af[fm] = *(bf16x8*)&As[wr * 32 + fm * 16 + lr][lks];
            #pragma unroll
            for (int fn = 0; fn < NF; ++fn)
                bfr[fn] = *(bf16x8*)&Bs[wc * (NF * 16) + fn * 16 + lr][lks];
            #pragma unroll
            for (int fm = 0; fm < 2; ++fm)
                #pragma unroll
                for (int fn = 0; fn < NF; ++fn)
                    acc[fm][fn] = __builtin_amdgcn_mfma_f32_16x16x32_bf16(
                        af[fm], bfr[fn], acc[fm][fn], 0, 0, 0);
        }
    }
}

// ---------------- fused LN2 + projections (grid 85 x 5) ----------------
__global__ __launch_bounds__(256) void proj_ln(
    const float* __restrict__ Ain, const float* __restrict__ pos,
    const float* __restrict__ g, const float* __restrict__ b,
    const unsigned short* __restrict__ WvT, const float* __restrict__ bv,
    const unsigned short* __restrict__ WofT, const float* __restrict__ bof,
    const unsigned short* __restrict__ WatT, const float* __restrict__ bat,
    unsigned short* __restrict__ value_bf, float* __restrict__ offraw,
    float* __restrict__ logits, float* __restrict__ xcur, int doLN)
{
    __shared__ short As[64][264];
    __shared__ short Bs[128][72];
    const int ny = blockIdx.y, mBase = blockIdx.x * 64;
    const unsigned short* Bp; const float* bias; int nBase, kind;
    if (ny < 2)      { Bp = WvT;  bias = bv;  nBase = ny * 128;       kind = 0; }
    else if (ny < 4) { Bp = WofT; bias = bof; nBase = (ny - 2) * 128; kind = 1; }
    else             { Bp = WatT; bias = bat; nBase = 0;              kind = 2; }

    prep_A(Ain, g, b, (kind > 0) ? pos : nullptr,
           (doLN && ny == 0) ? xcur : nullptr, mBase, doLN, As);

    f32x4 acc[2][4];
    core_Alds<4>(Bp, nBase, As, Bs, acc);

    const int lane = threadIdx.x & 63, wave = threadIdx.x >> 6;
    const int wr = wave >> 1, wc = wave & 1;
    #pragma unroll
    for (int fm = 0; fm < 2; ++fm)
        #pragma unroll
        for (int fn = 0; fn < 4; ++fn)
            #pragma unroll
            for (int r = 0; r < 4; ++r) {
                int m = mBase + wr * 32 + fm * 16 + (lane >> 4) * 4 + r;
                int n = nBase + wc * 64 + fn * 16 + (lane & 15);
                float v = acc[fm][fn][r] + bias[n];
                if (kind == 0)      value_bf[(long)m * 256 + n] = (unsigned short)f2bf(v);
                else if (kind == 1) offraw[(long)m * 256 + n] = v;
                else                logits[(long)m * 128 + n] = v;
            }
}

// ---------------- fused LN1 + W1 GEMM + relu (grid 85 x 8) ----------------
__global__ __launch_bounds__(256) void gemm_w1ln(
    const float* __restrict__ Ain, const float* __restrict__ g,
    const float* __restrict__ b, const unsigned short* __restrict__ W1T,
    const float* __restrict__ bias, unsigned short* __restrict__ hbuf,
    float* __restrict__ xout)
{
    __shared__ short As[64][264];
    __shared__ short Bs[128][72];
    const int mBase = blockIdx.x * 64, nBase = blockIdx.y * 128;

    prep_A(Ain, g, b, nullptr, (blockIdx.y == 0) ? xout : nullptr, mBase, 1, As);

    f32x4 acc[2][4];
    core_Alds<4>(W1T, nBase, As, Bs, acc);

    const int lane = threadIdx.x & 63, wave = threadIdx.x >> 6;
    const int wr = wave >> 1, wc = wave & 1;
    #pragma unroll
    for (int fm = 0; fm < 2; ++fm)
        #pragma unroll
        for (int fn = 0; fn < 4; ++fn)
            #pragma unroll
            for (int r = 0; r < 4; ++r) {
                int m = mBase + wr * 32 + fm * 16 + (lane >> 4) * 4 + r;
                int n = nBase + wc * 64 + fn * 16 + (lane & 15);
                float v = fmaxf(acc[fm][fn][r] + bias[n], 0.f);
                hbuf[(long)m * 1024 + n] = (unsigned short)f2bf(v);
            }
}

// ---------------- plain GEMM (N=256) + bias + residual -> fp32 (grid 85 x 4) ----------------
__global__ __launch_bounds__(256) void gemm_res(
    const unsigned short* __restrict__ A, const unsigned short* __restrict__ Bt,
    const float* __restrict__ bias, const float* __restrict__ res,
    float* __restrict__ out, int K)
{
    __shared__ short As[64][72];
    __shared__ short Bs[64][72];
    const int mBase = blockIdx.x * 64, nBase = blockIdx.y * 64;
    f32x4 acc[2][2];
    gemm_core<2>(A, Bt, K, mBase, nBase, As, Bs, acc);

    const int lane = threadIdx.x & 63, wave = threadIdx.x >> 6;
    const int wr = wave >> 1, wc = wave & 1;
    #pragma unroll
    for (int fm = 0; fm < 2; ++fm)
        #pragma unroll
        for (int fn = 0; fn < 2; ++fn)
            #pragma unroll
            for (int r = 0; r < 4; ++r) {
                int m = mBase + wr * 32 + fm * 16 + (lane >> 4) * 4 + r;
                int n = nBase + wc * 32 + fn * 16 + (lane & 15);
                out[(long)m * 256 + n] = acc[fm][fn][r] + bias[n] + res[(long)m * 256 + n];
            }
}

// ---------------- MSDA sampling v5: shfl reduce with coalesced lane layout ----------------
// Phase 2 mapping: h = tt>>4, pg = (tt>>2)&3, dq = tt&3.
// 4 consecutive lanes (dq 0..3) share the same gather row -> 64B segments (v3 coalescing);
// reduction over pg via shfl_xor(4), shfl_xor(8) -- no barrier, no LDS round trip (v4 win).
__global__ __launch_bounds__(256) void msda2(
    const unsigned short* __restrict__ value, const float* __restrict__ offraw,
    const float* __restrict__ logits, const float* __restrict__ vr,
    unsigned short* __restrict__ outB)
{
    const int t = threadIdx.x;
    const int q = t >> 7, tt = t & 127;
    const int s = blockIdx.x * 2 + q;

    __shared__ int4   sIdx[2][128];
    __shared__ float4 sW[2][128];

    {
        const int pt = tt & 15, l = pt >> 2;

        float lg = logits[(long)s * 128 + tt];
        float m = lg;
        #pragma unroll
        for (int o = 1; o < 16; o <<= 1) m = fmaxf(m, __shfl_xor(m, o));
        float e = expf(lg - m);
        float sum = e;
        #pragma unroll
        for (int o = 1; o < 16; o <<= 1) sum += __shfl_xor(sum, o);
        float aw = e / sum;

        int ls = (s < 4096) ? 0 : (s < 5120) ? 1 : (s < 5376) ? 2 : 3;
        int lw = c_logW[ls];
        int Wq = c_HW[ls];
        int rem = s - c_start[ls];
        int qi = rem >> lw, qj = rem & (Wq - 1);
        float xh = (qj + 0.5f) / (vr[ls * 2 + 1] * (float)Wq);
        float yh = (qi + 0.5f) / (vr[ls * 2 + 0] * (float)Wq);

        const int Wl = c_HW[l], sl = c_start[l];
        const float fW = (float)Wl;
        float refx = xh * vr[l * 2 + 1];
        float refy = yh * vr[l * 2 + 0];
        float2 oxy = *(const float2*)(offraw + (long)s * 256 + tt * 2);
        float x = refx * fW + oxy.x - 0.5f;
        float y = refy * fW + oxy.y - 0.5f;
        float x0f = floorf(x), y0f = floorf(y);
        float fx = x - x0f, fy = y - y0f;
        int x0 = (int)x0f, y0 = (int)y0f;
        int x1 = x0 + 1, y1 = y0 + 1;
        float vx0 = (x0 >= 0 && x0 < Wl) ? 1.f : 0.f;
        float vx1 = (x1 >= 0 && x1 < Wl) ? 1.f : 0.f;
        float vy0 = (y0 >= 0 && y0 < Wl) ? 1.f : 0.f;
        float vy1 = (y1 >= 0 && y1 < Wl) ? 1.f : 0.f;
        int cx0 = min(max(x0, 0), Wl - 1), cx1 = min(max(x1, 0), Wl - 1);
        int cy0 = min(max(y0, 0), Wl - 1), cy1 = min(max(y1, 0), Wl - 1);

        int4 id4;
        id4.x = sl + cy0 * Wl + cx0;
        id4.y = sl + cy0 * Wl + cx1;
        id4.z = sl + cy1 * Wl + cx0;
        id4.w = sl + cy1 * Wl + cx1;
        sIdx[q][tt] = id4;
        float4 w4;
        w4.x = aw * (1.f - fx) * (1.f - fy) * vx0 * vy0;
        w4.y = aw * fx * (1.f - fy) * vx1 * vy0;
        w4.z = aw * (1.f - fx) * fy * vx0 * vy1;
        w4.w = aw * fx * fy * vx1 * vy1;
        sW[q][tt] = w4;
    }
    __syncthreads();

    // phase 2: h = tt>>4, pg = (tt>>2)&3, dq = tt&3 (dq fastest -> coalesced)
    const int h = tt >> 4, pg = (tt >> 2) & 3, dq = tt & 3;
    const int cb = h * 32 + dq * 8;

    float a8[8] = {0.f,0.f,0.f,0.f,0.f,0.f,0.f,0.f};
    #pragma unroll
    for (int p = 0; p < 4; ++p) {
        const int ei = h * 16 + pg * 4 + p;
        int4 id = sIdx[q][ei];
        float4 w = sW[q][ei];
        u32x4 u0 = *(const u32x4*)(value + (long)id.x * 256 + cb);
        u32x4 u1 = *(const u32x4*)(value + (long)id.y * 256 + cb);
        u32x4 u2 = *(const u32x4*)(value + (long)id.z * 256 + cb);
        u32x4 u3 = *(const u32x4*)(value + (long)id.w * 256 + cb);
        #pragma unroll
        for (int j = 0; j < 4; ++j) {
            a8[2*j]   += w.x * lo_f(u0[j]) + w.y * lo_f(u1[j])
                       + w.z * lo_f(u2[j]) + w.w * lo_f(u3[j]);
            a8[2*j+1] += w.x * hi_f(u0[j]) + w.y * hi_f(u1[j])
                       + w.z * hi_f(u2[j]) + w.w * hi_f(u3[j]);
        }
    }
    // reduce over pg (lane bits 2-3, same wave)
    #pragma unroll
    for (int j = 0; j < 8; ++j) {
        a8[j] += __shfl_xor(a8[j], 4);
        a8[j] += __shfl_xor(a8[j], 8);
    }
    if (pg == 0) {
        short o8[8];
        #pragma unroll
        for (int j = 0; j < 8; ++j) o8[j] = f2bf(a8[j]);
        *(bf16x8*)(outB + (long)s * 256 + cb) = *(bf16x8*)o8;
    }
}

// ---------------- final LayerNorm: one wave per row ----------------
__global__ __launch_bounds__(256) void ln4f(
    const float* __restrict__ in, const float* __restrict__ g,
    const float* __restrict__ b, float* __restrict__ out)
{
    const int wave = threadIdx.x >> 6, lane = threadIdx.x & 63;
    const int s = blockIdx.x * 4 + wave;
    f32x4 v = *(const f32x4*)(in + (long)s * 256 + lane * 4);

    float sum = v[0] + v[1] + v[2] + v[3];
    #pragma unroll
    for (int o = 1; o < 64; o <<= 1) sum += __shfl_xor(sum, o);
    const float mean = sum * (1.f / 256.f);

    f32x4 d = v - mean;
    float sq = d[0]*d[0] + d[1]*d[1] + d[2]*d[2] + d[3]*d[3];
    #pragma unroll
    for (int o = 1; o < 64; o <<= 1) sq += __shfl_xor(sq, o);
    const float rstd = rsqrtf(sq * (1.f / 256.f) + 1e-5f);

    f32x4 gg = *(const f32x4*)(g + lane * 4);
    f32x4 bb = *(const f32x4*)(b + lane * 4);
    f32x4 o4 = d * rstd * gg + bb;
    *(f32x4*)(out + (long)s * 256 + lane * 4) = o4;
}

extern "C" void kernel_launch(void* const* d_in, const int* in_sizes, int n_in,
                              void* d_out, int out_size, void* d_ws, size_t ws_size,
                              hipStream_t stream) {
    const float* src   = (const float*)d_in[0];
    const float* pos   = (const float*)d_in[1];
    const float* vr    = (const float*)d_in[2];
    const float* Wv    = (const float*)d_in[5];
    const float* bv    = (const float*)d_in[6];
    const float* Woff  = (const float*)d_in[7];
    const float* boff  = (const float*)d_in[8];
    const float* Wattn = (const float*)d_in[9];
    const float* battn = (const float*)d_in[10];
    const float* Wout  = (const float*)d_in[11];
    const float* bout  = (const float*)d_in[12];
    const float* ln1g  = (const float*)d_in[13];
    const float* ln1b  = (const float*)d_in[14];
    const float* W1    = (const float*)d_in[15];
    const float* b1    = (const float*)d_in[16];
    const float* W2    = (const float*)d_in[17];
    const float* b2    = (const float*)d_in[18];
    const float* ln2g  = (const float*)d_in[19];
    const float* ln2b  = (const float*)d_in[20];

    const int S = S_TOT, C = C_DIM;
    const long SC = (long)S * C;

    float* ws     = (float*)d_ws;
    float* tmp2   = ws;                        // SC f32 (layer output, pre-LN2)
    float* xcur   = tmp2 + SC;                 // SC f32 (LN2 out = layer input x)
    float* offraw = xcur + SC;                 // SC f32 (aliased as xln1 after msda2)
    float* logits = offraw + SC;               // S*128 f32
    unsigned short* value_bf = (unsigned short*)(logits + (long)S * 128); // SC
    unsigned short* msda_bf  = value_bf + SC;  // SC
    unsigned short* hbuf_bf  = msda_bf + SC;   // S*F
    unsigned short* WT       = hbuf_bf + (long)S * F_DIM;

    float* xln1 = offraw;

    const unsigned short* WvT  = WT + 0;
    const unsigned short* WofT = WT + 393216;
    const unsigned short* WatT = WT + 786432;
    const unsigned short* WouT = WT + 983040;
    const unsigned short* W1T  = WT + 1376256;
    const unsigned short* W2T  = WT + 2949120;

    prep_weights<<<1104, 256, 0, stream>>>(Wv, Woff, Wattn, Wout, W1, W2, WT);

    for (int i = 0; i < N_LAYERS; ++i) {
        const float* Ain = (i == 0) ? src : tmp2;
        const float* g2  = (i == 0) ? nullptr : ln2g + (long)(i - 1) * C;
        const float* bb2 = (i == 0) ? nullptr : ln2b + (long)(i - 1) * C;
        const float* resWout = (i == 0) ? src : xcur;

        proj_ln<<<dim3(85, 5), 256, 0, stream>>>(
            Ain, pos, g2, bb2,
            WvT + (long)i * 65536, bv + (long)i * C,
            WofT + (long)i * 65536, boff + (long)i * 256,
            WatT + (long)i * 32768, battn + (long)i * 128,
            value_bf, offraw, logits, xcur, (i == 0) ? 0 : 1);

        msda2<<<S / 2, 256, 0, stream>>>(value_bf, offraw, logits, vr, msda_bf);

        gemm_res<<<dim3(85, 4), 256, 0, stream>>>(
            msda_bf, WouT + (long)i * 65536, bout + (long)i * C, resWout, tmp2, 256);

        gemm_w1ln<<<dim3(85, 8), 256, 0, stream>>>(
            tmp2, ln1g + (long)i * C, ln1b + (long)i * C,
            W1T + (long)i * 262144, b1 + (long)i * F_DIM, hbuf_bf, xln1);

        gemm_res<<<dim3(85, 4), 256, 0, stream>>>(
            hbuf_bf, W2T + (long)i * 262144, b2 + (long)i * C, xln1, tmp2, 1024);
    }

    ln4f<<<S / 4, 256, 0, stream>>>(
        tmp2, ln2g + (long)(N_LAYERS - 1) * C, ln2b + (long)(N_LAYERS - 1) * C,
        (float*)d_out);
}

// Round 11
// 466.089 us; speedup vs baseline: 1.6980x; 1.0803x over previous
//
#include <hip/hip_runtime.h>
#include <hip/hip_bf16.h>

#define S_TOT 5440
#define C_DIM 256
#define F_DIM 1024
#define N_LAYERS 6

__device__ __constant__ int c_HW[4]    = {64, 32, 16, 8};
__device__ __constant__ int c_logW[4]  = {6, 5, 4, 3};
__device__ __constant__ int c_start[4] = {0, 4096, 5120, 5376};

typedef __attribute__((ext_vector_type(8))) short bf16x8;
typedef __attribute__((ext_vector_type(4))) float f32x4;
typedef __attribute__((ext_vector_type(4))) unsigned int u32x4;

__device__ __forceinline__ short f2bf(float f) {
    __hip_bfloat16 h = __float2bfloat16(f);
    return *reinterpret_cast<short*>(&h);
}
union uf32 { unsigned int u; float f; };
__device__ __forceinline__ float lo_f(unsigned int u) { uf32 c; c.u = u << 16;          return c.f; }
__device__ __forceinline__ float hi_f(unsigned int u) { uf32 c; c.u = u & 0xffff0000u; return c.f; }
__device__ __forceinline__ float bf2f(unsigned short u) { uf32 c; c.u = ((unsigned int)u) << 16; return c.f; }

// ---------------- weight prep: fp32 [K][N] -> bf16 [N][K], all 36 matrices ----------------
__global__ __launch_bounds__(256) void prep_weights(
    const float* __restrict__ Wv, const float* __restrict__ Woff,
    const float* __restrict__ Wattn, const float* __restrict__ Wout,
    const float* __restrict__ W1, const float* __restrict__ W2,
    unsigned short* __restrict__ WT)
{
    __shared__ short T[64][72];
    const int bid = blockIdx.x;
    const int layer = bid / 184;
    const int r = bid % 184;
    const float* src; unsigned short* dst; int K, N, kb, nb;
    if (r < 16)       { src = Wv    + (long)layer*65536;  dst = WT + 0       + (long)layer*65536;  K=256;  N=256;  kb=r&3;        nb=r>>2; }
    else if (r < 32)  { src = Woff  + (long)layer*65536;  dst = WT + 393216  + (long)layer*65536;  K=256;  N=256;  kb=(r-16)&3;   nb=(r-16)>>2; }
    else if (r < 40)  { src = Wattn + (long)layer*32768;  dst = WT + 786432  + (long)layer*32768;  K=256;  N=128;  kb=(r-32)&3;   nb=(r-32)>>2; }
    else if (r < 56)  { src = Wout  + (long)layer*65536;  dst = WT + 983040  + (long)layer*65536;  K=256;  N=256;  kb=(r-40)&3;   nb=(r-40)>>2; }
    else if (r < 120) { src = W1    + (long)layer*262144; dst = WT + 1376256 + (long)layer*262144; K=256;  N=1024; kb=(r-56)&3;   nb=(r-56)>>2; }
    else              { src = W2    + (long)layer*262144; dst = WT + 2949120 + (long)layer*262144; K=1024; N=256;  kb=(r-120)&15; nb=(r-120)>>4; }
    const int k0 = kb * 64, n0 = nb * 64;
    const int t = threadIdx.x;
    {
        const int row = t >> 2, cg = (t & 3) * 16;
        const float* sp = src + (long)(k0 + row) * N + n0 + cg;
        float4 v0 = *(const float4*)sp;
        float4 v1 = *(const float4*)(sp + 4);
        float4 v2 = *(const float4*)(sp + 8);
        float4 v3 = *(const float4*)(sp + 12);
        short tmp[16];
        tmp[0]=f2bf(v0.x); tmp[1]=f2bf(v0.y); tmp[2]=f2bf(v0.z); tmp[3]=f2bf(v0.w);
        tmp[4]=f2bf(v1.x); tmp[5]=f2bf(v1.y); tmp[6]=f2bf(v1.z); tmp[7]=f2bf(v1.w);
        tmp[8]=f2bf(v2.x); tmp[9]=f2bf(v2.y); tmp[10]=f2bf(v2.z); tmp[11]=f2bf(v2.w);
        tmp[12]=f2bf(v3.x); tmp[13]=f2bf(v3.y); tmp[14]=f2bf(v3.z); tmp[15]=f2bf(v3.w);
        *(bf16x8*)&T[row][cg]     = *(bf16x8*)&tmp[0];
        *(bf16x8*)&T[row][cg + 8] = *(bf16x8*)&tmp[8];
    }
    __syncthreads();
    {
        const int n = t >> 2, kg = (t & 3) * 16;
        short o[16];
        #pragma unroll
        for (int j = 0; j < 16; ++j) o[j] = T[kg + j][n];
        unsigned short* dp = dst + (long)(n0 + n) * K + k0 + kg;
        *(bf16x8*)dp       = *(bf16x8*)&o[0];
        *(bf16x8*)(dp + 8) = *(bf16x8*)&o[8];
    }
}

// ============ A-prep: load fp32 64x256 tile, optional LN, optional +pos, -> bf16 LDS ============
__device__ __forceinline__ void prep_A(
    const float* __restrict__ Ain, const float* __restrict__ g,
    const float* __restrict__ b, const float* __restrict__ pos,
    float* __restrict__ xout, int mBase, int doLN,
    short (*As)[264])
{
    const int t = threadIdx.x;
    const int row = t >> 2, q4 = t & 3;
    const long gbase = (long)(mBase + row) * 256 + q4 * 64;
    float va[64];
    #pragma unroll
    for (int j = 0; j < 16; ++j) {
        float4 v = *(const float4*)(Ain + gbase + j * 4);
        va[j*4+0] = v.x; va[j*4+1] = v.y; va[j*4+2] = v.z; va[j*4+3] = v.w;
    }
    if (doLN) {
        float s1 = 0.f, s2 = 0.f;
        #pragma unroll
        for (int j = 0; j < 64; ++j) { s1 += va[j]; s2 += va[j] * va[j]; }
        s1 += __shfl_xor(s1, 1); s2 += __shfl_xor(s2, 1);
        s1 += __shfl_xor(s1, 2); s2 += __shfl_xor(s2, 2);
        const float mean = s1 * (1.f / 256.f);
        const float var  = s2 * (1.f / 256.f) - mean * mean;
        const float rstd = rsqrtf(var + 1e-5f);
        #pragma unroll
        for (int j = 0; j < 16; ++j) {
            float4 g4 = *(const float4*)(g + q4 * 64 + j * 4);
            float4 b4 = *(const float4*)(b + q4 * 64 + j * 4);
            va[j*4+0] = (va[j*4+0] - mean) * rstd * g4.x + b4.x;
            va[j*4+1] = (va[j*4+1] - mean) * rstd * g4.y + b4.y;
            va[j*4+2] = (va[j*4+2] - mean) * rstd * g4.z + b4.z;
            va[j*4+3] = (va[j*4+3] - mean) * rstd * g4.w + b4.w;
        }
    }
    if (xout) {
        #pragma unroll
        for (int j = 0; j < 16; ++j) {
            float4 v;
            v.x = va[j*4+0]; v.y = va[j*4+1]; v.z = va[j*4+2]; v.w = va[j*4+3];
            *(float4*)(xout + gbase + j * 4) = v;
        }
    }
    if (pos) {
        #pragma unroll
        for (int j = 0; j < 16; ++j) {
            float4 p = *(const float4*)(pos + gbase + j * 4);
            va[j*4+0] += p.x; va[j*4+1] += p.y; va[j*4+2] += p.z; va[j*4+3] += p.w;
        }
    }
    #pragma unroll
    for (int j8 = 0; j8 < 8; ++j8) {
        short tmp[8];
        #pragma unroll
        for (int e = 0; e < 8; ++e) tmp[e] = f2bf(va[j8 * 8 + e]);
        *(bf16x8*)&As[row][q4 * 64 + j8 * 8] = *(bf16x8*)tmp;
    }
}

// ============ GEMM core with A resident in LDS (K=256), B streamed ============
template<int NF>
__device__ __forceinline__ void core_Alds(
    const unsigned short* __restrict__ Bt, int nBase,
    const short (*As)[264], short (*Bs)[72], f32x4 (&acc)[2][NF])
{
    const int t = threadIdx.x;
    const int lane = t & 63, wave = t >> 6;
    const int wr = wave >> 1, wc = wave & 1;
    const int lr = lane & 15;

    #pragma unroll
    for (int i = 0; i < 2; ++i)
        #pragma unroll
        for (int j = 0; j < NF; ++j)
            acc[i][j] = (f32x4){0.f, 0.f, 0.f, 0.f};

    for (int k0 = 0; k0 < 256; k0 += 64) {
        bf16x8 rb[NF];
        #pragma unroll
        for (int q = 0; q < NF; ++q) {
            int flat = q * 256 + t, row = flat >> 3, cg = (flat & 7) * 8;
            rb[q] = *(const bf16x8*)(Bt + (long)(nBase + row) * 256 + k0 + cg);
        }
        __syncthreads();
        #pragma unroll
        for (int q = 0; q < NF; ++q) {
            int flat = q * 256 + t, row = flat >> 3, cg = (flat & 7) * 8;
            *(bf16x8*)&Bs[row][cg] = rb[q];
        }
        __syncthreads();
        #pragma unroll
        for (int kk = 0; kk < 2; ++kk) {
            const int lks = kk * 32 + (lane >> 4) * 8;
            bf16x8 af[2], bfr[NF];
            #pragma unroll
            for (int fm = 0; fm < 2; ++fm)
                af[fm] = *(const bf16x8*)&As[wr * 32 + fm * 16 + lr][k0 + lks];
            #pragma unroll
            for (int fn = 0; fn < NF; ++fn)
                bfr[fn] = *(bf16x8*)&Bs[wc * (NF * 16) + fn * 16 + lr][lks];
            #pragma unroll
            for (int fm = 0; fm < 2; ++fm)
                #pragma unroll
                for (int fn = 0; fn < NF; ++fn)
                    acc[fm][fn] = __builtin_amdgcn_mfma_f32_16x16x32_bf16(
                        af[fm], bfr[fn], acc[fm][fn], 0, 0, 0);
        }
    }
}

// ============ GEMM core with bf16 A from global (round-4 proven) ============
template<int NF>
__device__ __forceinline__ void gemm_core(
    const unsigned short* __restrict__ A, const unsigned short* __restrict__ Bt,
    int K, int mBase, int nBase, short (*As)[72], short (*Bs)[72],
    f32x4 (&acc)[2][NF])
{
    const int t = threadIdx.x;
    const int lane = t & 63, wave = t >> 6;
    const int wr = wave >> 1, wc = wave & 1;
    const int lr = lane & 15;

    #pragma unroll
    for (int i = 0; i < 2; ++i)
        #pragma unroll
        for (int j = 0; j < NF; ++j)
            acc[i][j] = (f32x4){0.f, 0.f, 0.f, 0.f};

    for (int k0 = 0; k0 < K; k0 += 64) {
        bf16x8 ra[2], rb[NF];
        #pragma unroll
        for (int q = 0; q < 2; ++q) {
            int flat = q * 256 + t, row = flat >> 3, cg = (flat & 7) * 8;
            ra[q] = *(const bf16x8*)(A + (long)(mBase + row) * K + k0 + cg);
        }
        #pragma unroll
        for (int q = 0; q < NF; ++q) {
            int flat = q * 256 + t, row = flat >> 3, cg = (flat & 7) * 8;
            rb[q] = *(const bf16x8*)(Bt + (long)(nBase + row) * K + k0 + cg);
        }
        __syncthreads();
        #pragma unroll
        for (int q = 0; q < 2; ++q) {
            int flat = q * 256 + t, row = flat >> 3, cg = (flat & 7) * 8;
            *(bf16x8*)&As[row][cg] = ra[q];
        }
        #pragma unroll
        for (int q = 0; q < NF; ++q) {
            int flat = q * 256 + t, row = flat >> 3, cg = (flat & 7) * 8;
            *(bf16x8*)&Bs[row][cg] = rb[q];
        }
        __syncthreads();
        #pragma unroll
        for (int kk = 0; kk < 2; ++kk) {
            const int lks = kk * 32 + (lane >> 4) * 8;
            bf16x8 af[2], bfr[NF];
            #pragma unroll
            for (int fm = 0; fm < 2; ++fm)
                af[fm] = *(bf16x8*)&As[wr * 32 + fm * 16 + lr][lks];
            #pragma unroll
            for (int fn = 0; fn < NF; ++fn)
                bfr[fn] = *(bf16x8*)&Bs[wc * (NF * 16) + fn * 16 + lr][lks];
            #pragma unroll
            for (int fm = 0; fm < 2; ++fm)
                #pragma unroll
                for (int fn = 0; fn < NF; ++fn)
                    acc[fm][fn] = __builtin_amdgcn_mfma_f32_16x16x32_bf16(
                        af[fm], bfr[fn], acc[fm][fn], 0, 0, 0);
        }
    }
}

// ---------------- fused LN2 + projections (grid 85 x 5); offraw/logits now bf16 ----------------
__global__ __launch_bounds__(256) void proj_ln(
    const float* __restrict__ Ain, const float* __restrict__ pos,
    const float* __restrict__ g, const float* __restrict__ b,
    const unsigned short* __restrict__ WvT, const float* __restrict__ bv,
    const unsigned short* __restrict__ WofT, const float* __restrict__ bof,
    const unsigned short* __restrict__ WatT, const float* __restrict__ bat,
    unsigned short* __restrict__ value_bf, unsigned short* __restrict__ offraw,
    unsigned short* __restrict__ logits, float* __restrict__ xcur, int doLN)
{
    __shared__ short As[64][264];
    __shared__ short Bs[128][72];
    const int ny = blockIdx.y, mBase = blockIdx.x * 64;
    const unsigned short* Bp; const float* bias; int nBase, kind;
    if (ny < 2)      { Bp = WvT;  bias = bv;  nBase = ny * 128;       kind = 0; }
    else if (ny < 4) { Bp = WofT; bias = bof; nBase = (ny - 2) * 128; kind = 1; }
    else             { Bp = WatT; bias = bat; nBase = 0;              kind = 2; }

    prep_A(Ain, g, b, (kind > 0) ? pos : nullptr,
           (doLN && ny == 0) ? xcur : nullptr, mBase, doLN, As);

    f32x4 acc[2][4];
    core_Alds<4>(Bp, nBase, As, Bs, acc);

    const int lane = threadIdx.x & 63, wave = threadIdx.x >> 6;
    const int wr = wave >> 1, wc = wave & 1;
    #pragma unroll
    for (int fm = 0; fm < 2; ++fm)
        #pragma unroll
        for (int fn = 0; fn < 4; ++fn)
            #pragma unroll
            for (int r = 0; r < 4; ++r) {
                int m = mBase + wr * 32 + fm * 16 + (lane >> 4) * 4 + r;
                int n = nBase + wc * 64 + fn * 16 + (lane & 15);
                float v = acc[fm][fn][r] + bias[n];
                if (kind == 0)      value_bf[(long)m * 256 + n] = (unsigned short)f2bf(v);
                else if (kind == 1) offraw[(long)m * 256 + n] = (unsigned short)f2bf(v);
                else                logits[(long)m * 128 + n] = (unsigned short)f2bf(v);
            }
}

// ---------------- fused LN1 + W1 GEMM + relu (grid 85 x 4, NF=8, 64x256 tile) ----------------
__global__ __launch_bounds__(256) void gemm_w1ln(
    const float* __restrict__ Ain, const float* __restrict__ g,
    const float* __restrict__ b, const unsigned short* __restrict__ W1T,
    const float* __restrict__ bias, unsigned short* __restrict__ hbuf,
    float* __restrict__ xout)
{
    __shared__ short As[64][264];
    __shared__ short Bs[256][72];
    const int mBase = blockIdx.x * 64, nBase = blockIdx.y * 256;

    prep_A(Ain, g, b, nullptr, (blockIdx.y == 0) ? xout : nullptr, mBase, 1, As);

    f32x4 acc[2][8];
    core_Alds<8>(W1T, nBase, As, Bs, acc);

    const int lane = threadIdx.x & 63, wave = threadIdx.x >> 6;
    const int wr = wave >> 1, wc = wave & 1;
    #pragma unroll
    for (int fm = 0; fm < 2; ++fm)
        #pragma unroll
        for (int fn = 0; fn < 8; ++fn)
            #pragma unroll
            for (int r = 0; r < 4; ++r) {
                int m = mBase + wr * 32 + fm * 16 + (lane >> 4) * 4 + r;
                int n = nBase + wc * 128 + fn * 16 + (lane & 15);
                float v = fmaxf(acc[fm][fn][r] + bias[n], 0.f);
                hbuf[(long)m * 1024 + n] = (unsigned short)f2bf(v);
            }
}

// ---------------- plain GEMM (N=256) + bias + residual -> fp32 (grid 85 x 4) ----------------
__global__ __launch_bounds__(256) void gemm_res(
    const unsigned short* __restrict__ A, const unsigned short* __restrict__ Bt,
    const float* __restrict__ bias, const float* __restrict__ res,
    float* __restrict__ out, int K)
{
    __shared__ short As[64][72];
    __shared__ short Bs[64][72];
    const int mBase = blockIdx.x * 64, nBase = blockIdx.y * 64;
    f32x4 acc[2][2];
    gemm_core<2>(A, Bt, K, mBase, nBase, As, Bs, acc);

    const int lane = threadIdx.x & 63, wave = threadIdx.x >> 6;
    const int wr = wave >> 1, wc = wave & 1;
    #pragma unroll
    for (int fm = 0; fm < 2; ++fm)
        #pragma unroll
        for (int fn = 0; fn < 2; ++fn)
            #pragma unroll
            for (int r = 0; r < 4; ++r) {
                int m = mBase + wr * 32 + fm * 16 + (lane >> 4) * 4 + r;
                int n = nBase + wc * 32 + fn * 16 + (lane & 15);
                out[(long)m * 256 + n] = acc[fm][fn][r] + bias[n] + res[(long)m * 256 + n];
            }
}

// ---------------- MSDA sampling v5b: bf16 offraw/logits inputs ----------------
__global__ __launch_bounds__(256) void msda2(
    const unsigned short* __restrict__ value, const unsigned short* __restrict__ offraw,
    const unsigned short* __restrict__ logits, const float* __restrict__ vr,
    unsigned short* __restrict__ outB)
{
    const int t = threadIdx.x;
    const int q = t >> 7, tt = t & 127;
    const int s = blockIdx.x * 2 + q;

    __shared__ int4   sIdx[2][128];
    __shared__ float4 sW[2][128];

    {
        const int pt = tt & 15, l = pt >> 2;

        float lg = bf2f(logits[(long)s * 128 + tt]);
        float m = lg;
        #pragma unroll
        for (int o = 1; o < 16; o <<= 1) m = fmaxf(m, __shfl_xor(m, o));
        float e = expf(lg - m);
        float sum = e;
        #pragma unroll
        for (int o = 1; o < 16; o <<= 1) sum += __shfl_xor(sum, o);
        float aw = e / sum;

        int ls = (s < 4096) ? 0 : (s < 5120) ? 1 : (s < 5376) ? 2 : 3;
        int lw = c_logW[ls];
        int Wq = c_HW[ls];
        int rem = s - c_start[ls];
        int qi = rem >> lw, qj = rem & (Wq - 1);
        float xh = (qj + 0.5f) / (vr[ls * 2 + 1] * (float)Wq);
        float yh = (qi + 0.5f) / (vr[ls * 2 + 0] * (float)Wq);

        const int Wl = c_HW[l], sl = c_start[l];
        const float fW = (float)Wl;
        float refx = xh * vr[l * 2 + 1];
        float refy = yh * vr[l * 2 + 0];
        unsigned int uoxy = *(const unsigned int*)(offraw + (long)s * 256 + tt * 2);
        float ox = lo_f(uoxy), oy = hi_f(uoxy);
        float x = refx * fW + ox - 0.5f;
        float y = refy * fW + oy - 0.5f;
        float x0f = floorf(x), y0f = floorf(y);
        float fx = x - x0f, fy = y - y0f;
        int x0 = (int)x0f, y0 = (int)y0f;
        int x1 = x0 + 1, y1 = y0 + 1;
        float vx0 = (x0 >= 0 && x0 < Wl) ? 1.f : 0.f;
        float vx1 = (x1 >= 0 && x1 < Wl) ? 1.f : 0.f;
        float vy0 = (y0 >= 0 && y0 < Wl) ? 1.f : 0.f;
        float vy1 = (y1 >= 0 && y1 < Wl) ? 1.f : 0.f;
        int cx0 = min(max(x0, 0), Wl - 1), cx1 = min(max(x1, 0), Wl - 1);
        int cy0 = min(max(y0, 0), Wl - 1), cy1 = min(max(y1, 0), Wl - 1);

        int4 id4;
        id4.x = sl + cy0 * Wl + cx0;
        id4.y = sl + cy0 * Wl + cx1;
        id4.z = sl + cy1 * Wl + cx0;
        id4.w = sl + cy1 * Wl + cx1;
        sIdx[q][tt] = id4;
        float4 w4;
        w4.x = aw * (1.f - fx) * (1.f - fy) * vx0 * vy0;
        w4.y = aw * fx * (1.f - fy) * vx1 * vy0;
        w4.z = aw * (1.f - fx) * fy * vx0 * vy1;
        w4.w = aw * fx * fy * vx1 * vy1;
        sW[q][tt] = w4;
    }
    __syncthreads();

    // phase 2: h = tt>>4, pg = (tt>>2)&3, dq = tt&3 (dq fastest -> coalesced)
    const int h = tt >> 4, pg = (tt >> 2) & 3, dq = tt & 3;
    const int cb = h * 32 + dq * 8;

    float a8[8] = {0.f,0.f,0.f,0.f,0.f,0.f,0.f,0.f};
    #pragma unroll
    for (int p = 0; p < 4; ++p) {
        const int ei = h * 16 + pg * 4 + p;
        int4 id = sIdx[q][ei];
        float4 w = sW[q][ei];
        u32x4 u0 = *(const u32x4*)(value + (long)id.x * 256 + cb);
        u32x4 u1 = *(const u32x4*)(value + (long)id.y * 256 + cb);
        u32x4 u2 = *(const u32x4*)(value + (long)id.z * 256 + cb);
        u32x4 u3 = *(const u32x4*)(value + (long)id.w * 256 + cb);
        #pragma unroll
        for (int j = 0; j < 4; ++j) {
            a8[2*j]   += w.x * lo_f(u0[j]) + w.y * lo_f(u1[j])
                       + w.z * lo_f(u2[j]) + w.w * lo_f(u3[j]);
            a8[2*j+1] += w.x * hi_f(u0[j]) + w.y * hi_f(u1[j])
                       + w.z * hi_f(u2[j]) + w.w * hi_f(u3[j]);
        }
    }
    // reduce over pg (lane bits 2-3, same wave)
    #pragma unroll
    for (int j = 0; j < 8; ++j) {
        a8[j] += __shfl_xor(a8[j], 4);
        a8[j] += __shfl_xor(a8[j], 8);
    }
    if (pg == 0) {
        short o8[8];
        #pragma unroll
        for (int j = 0; j < 8; ++j) o8[j] = f2bf(a8[j]);
        *(bf16x8*)(outB + (long)s * 256 + cb) = *(bf16x8*)o8;
    }
}

// ---------------- final LayerNorm: one wave per row ----------------
__global__ __launch_bounds__(256) void ln4f(
    const float* __restrict__ in, const float* __restrict__ g,
    const float* __restrict__ b, float* __restrict__ out)
{
    const int wave = threadIdx.x >> 6, lane = threadIdx.x & 63;
    const int s = blockIdx.x * 4 + wave;
    f32x4 v = *(const f32x4*)(in + (long)s * 256 + lane * 4);

    float sum = v[0] + v[1] + v[2] + v[3];
    #pragma unroll
    for (int o = 1; o < 64; o <<= 1) sum += __shfl_xor(sum, o);
    const float mean = sum * (1.f / 256.f);

    f32x4 d = v - mean;
    float sq = d[0]*d[0] + d[1]*d[1] + d[2]*d[2] + d[3]*d[3];
    #pragma unroll
    for (int o = 1; o < 64; o <<= 1) sq += __shfl_xor(sq, o);
    const float rstd = rsqrtf(sq * (1.f / 256.f) + 1e-5f);

    f32x4 gg = *(const f32x4*)(g + lane * 4);
    f32x4 bb = *(const f32x4*)(b + lane * 4);
    f32x4 o4 = d * rstd * gg + bb;
    *(f32x4*)(out + (long)s * 256 + lane * 4) = o4;
}

extern "C" void kernel_launch(void* const* d_in, const int* in_sizes, int n_in,
                              void* d_out, int out_size, void* d_ws, size_t ws_size,
                              hipStream_t stream) {
    const float* src   = (const float*)d_in[0];
    const float* pos   = (const float*)d_in[1];
    const float* vr    = (const float*)d_in[2];
    const float* Wv    = (const float*)d_in[5];
    const float* bv    = (const float*)d_in[6];
    const float* Woff  = (const float*)d_in[7];
    const float* boff  = (const float*)d_in[8];
    const float* Wattn = (const float*)d_in[9];
    const float* battn = (const float*)d_in[10];
    const float* Wout  = (const float*)d_in[11];
    const float* bout  = (const float*)d_in[12];
    const float* ln1g  = (const float*)d_in[13];
    const float* ln1b  = (const float*)d_in[14];
    const float* W1    = (const float*)d_in[15];
    const float* b1    = (const float*)d_in[16];
    const float* W2    = (const float*)d_in[17];
    const float* b2    = (const float*)d_in[18];
    const float* ln2g  = (const float*)d_in[19];
    const float* ln2b  = (const float*)d_in[20];

    const int S = S_TOT, C = C_DIM;
    const long SC = (long)S * C;

    // fp32 region
    float* ws     = (float*)d_ws;
    float* tmp2   = ws;                        // SC f32 (layer output, pre-LN2)
    float* xcur   = tmp2 + SC;                 // SC f32 (LN2 out = layer input x)
    float* xln1   = xcur + SC;                 // SC f32 (LN1 out, residual for W2)
    // bf16 region
    unsigned short* offraw_bf = (unsigned short*)(xln1 + SC);      // SC
    unsigned short* logits_bf = offraw_bf + SC;                    // S*128
    unsigned short* value_bf  = logits_bf + (long)S * 128;         // SC
    unsigned short* msda_bf   = value_bf + SC;                     // SC
    unsigned short* hbuf_bf   = msda_bf + SC;                      // S*F
    unsigned short* WT        = hbuf_bf + (long)S * F_DIM;         // 4521984

    const unsigned short* WvT  = WT + 0;
    const unsigned short* WofT = WT + 393216;
    const unsigned short* WatT = WT + 786432;
    const unsigned short* WouT = WT + 983040;
    const unsigned short* W1T  = WT + 1376256;
    const unsigned short* W2T  = WT + 2949120;

    prep_weights<<<1104, 256, 0, stream>>>(Wv, Woff, Wattn, Wout, W1, W2, WT);

    for (int i = 0; i < N_LAYERS; ++i) {
        const float* Ain = (i == 0) ? src : tmp2;
        const float* g2  = (i == 0) ? nullptr : ln2g + (long)(i - 1) * C;
        const float* bb2 = (i == 0) ? nullptr : ln2b + (long)(i - 1) * C;
        const float* resWout = (i == 0) ? src : xcur;

        proj_ln<<<dim3(85, 5), 256, 0, stream>>>(
            Ain, pos, g2, bb2,
            WvT + (long)i * 65536, bv + (long)i * C,
            WofT + (long)i * 65536, boff + (long)i * 256,
            WatT + (long)i * 32768, battn + (long)i * 128,
            value_bf, offraw_bf, logits_bf, xcur, (i == 0) ? 0 : 1);

        msda2<<<S / 2, 256, 0, stream>>>(value_bf, offraw_bf, logits_bf, vr, msda_bf);

        gemm_res<<<dim3(85, 4), 256, 0, stream>>>(
            msda_bf, WouT + (long)i * 65536, bout + (long)i * C, resWout, tmp2, 256);

        gemm_w1ln<<<dim3(85, 4), 256, 0, stream>>>(
            tmp2, ln1g + (long)i * C, ln1b + (long)i * C,
            W1T + (long)i * 262144, b1 + (long)i * F_DIM, hbuf_bf, xln1);

        gemm_res<<<dim3(85, 4), 256, 0, stream>>>(
            hbuf_bf, W2T + (long)i * 262144, b2 + (long)i * C, xln1, tmp2, 1024);
    }

    ln4f<<<S / 4, 256, 0, stream>>>(
        tmp2, ln2g + (long)(N_LAYERS - 1) * C, ln2b + (long)(N_LAYERS - 1) * C,
        (float*)d_out);
}

// Round 12
// 431.432 us; speedup vs baseline: 1.8344x; 1.0803x over previous
//
#include <hip/hip_runtime.h>
#include <hip/hip_bf16.h>

#define S_TOT 5440
#define C_DIM 256
#define F_DIM 1024
#define N_LAYERS 6

__device__ __constant__ int c_HW[4]    = {64, 32, 16, 8};
__device__ __constant__ int c_logW[4]  = {6, 5, 4, 3};
__device__ __constant__ int c_start[4] = {0, 4096, 5120, 5376};

typedef __attribute__((ext_vector_type(8))) short bf16x8;
typedef __attribute__((ext_vector_type(4))) float f32x4;
typedef __attribute__((ext_vector_type(4))) unsigned int u32x4;

__device__ __forceinline__ short f2bf(float f) {
    __hip_bfloat16 h = __float2bfloat16(f);
    return *reinterpret_cast<short*>(&h);
}
union uf32 { unsigned int u; float f; };
__device__ __forceinline__ float lo_f(unsigned int u) { uf32 c; c.u = u << 16;          return c.f; }
__device__ __forceinline__ float hi_f(unsigned int u) { uf32 c; c.u = u & 0xffff0000u; return c.f; }
__device__ __forceinline__ float bf2f(unsigned short u) { uf32 c; c.u = ((unsigned int)u) << 16; return c.f; }

// ---------------- weight prep: fp32 [K][N] -> bf16 [N][K], all 36 matrices ----------------
__global__ __launch_bounds__(256) void prep_weights(
    const float* __restrict__ Wv, const float* __restrict__ Woff,
    const float* __restrict__ Wattn, const float* __restrict__ Wout,
    const float* __restrict__ W1, const float* __restrict__ W2,
    unsigned short* __restrict__ WT)
{
    __shared__ short T[64][72];
    const int bid = blockIdx.x;
    const int layer = bid / 184;
    const int r = bid % 184;
    const float* src; unsigned short* dst; int K, N, kb, nb;
    if (r < 16)       { src = Wv    + (long)layer*65536;  dst = WT + 0       + (long)layer*65536;  K=256;  N=256;  kb=r&3;        nb=r>>2; }
    else if (r < 32)  { src = Woff  + (long)layer*65536;  dst = WT + 393216  + (long)layer*65536;  K=256;  N=256;  kb=(r-16)&3;   nb=(r-16)>>2; }
    else if (r < 40)  { src = Wattn + (long)layer*32768;  dst = WT + 786432  + (long)layer*32768;  K=256;  N=128;  kb=(r-32)&3;   nb=(r-32)>>2; }
    else if (r < 56)  { src = Wout  + (long)layer*65536;  dst = WT + 983040  + (long)layer*65536;  K=256;  N=256;  kb=(r-40)&3;   nb=(r-40)>>2; }
    else if (r < 120) { src = W1    + (long)layer*262144; dst = WT + 1376256 + (long)layer*262144; K=256;  N=1024; kb=(r-56)&3;   nb=(r-56)>>2; }
    else              { src = W2    + (long)layer*262144; dst = WT + 2949120 + (long)layer*262144; K=1024; N=256;  kb=(r-120)&15; nb=(r-120)>>4; }
    const int k0 = kb * 64, n0 = nb * 64;
    const int t = threadIdx.x;
    {
        const int row = t >> 2, cg = (t & 3) * 16;
        const float* sp = src + (long)(k0 + row) * N + n0 + cg;
        float4 v0 = *(const float4*)sp;
        float4 v1 = *(const float4*)(sp + 4);
        float4 v2 = *(const float4*)(sp + 8);
        float4 v3 = *(const float4*)(sp + 12);
        short tmp[16];
        tmp[0]=f2bf(v0.x); tmp[1]=f2bf(v0.y); tmp[2]=f2bf(v0.z); tmp[3]=f2bf(v0.w);
        tmp[4]=f2bf(v1.x); tmp[5]=f2bf(v1.y); tmp[6]=f2bf(v1.z); tmp[7]=f2bf(v1.w);
        tmp[8]=f2bf(v2.x); tmp[9]=f2bf(v2.y); tmp[10]=f2bf(v2.z); tmp[11]=f2bf(v2.w);
        tmp[12]=f2bf(v3.x); tmp[13]=f2bf(v3.y); tmp[14]=f2bf(v3.z); tmp[15]=f2bf(v3.w);
        *(bf16x8*)&T[row][cg]     = *(bf16x8*)&tmp[0];
        *(bf16x8*)&T[row][cg + 8] = *(bf16x8*)&tmp[8];
    }
    __syncthreads();
    {
        const int n = t >> 2, kg = (t & 3) * 16;
        short o[16];
        #pragma unroll
        for (int j = 0; j < 16; ++j) o[j] = T[kg + j][n];
        unsigned short* dp = dst + (long)(n0 + n) * K + k0 + kg;
        *(bf16x8*)dp       = *(bf16x8*)&o[0];
        *(bf16x8*)(dp + 8) = *(bf16x8*)&o[8];
    }
}

// ============ A-prep (32 rows): fp32 32x256 tile, optional LN/+pos/xout, -> bf16 LDS ============
__device__ __forceinline__ void prep_A32(
    const float* __restrict__ Ain, const float* __restrict__ g,
    const float* __restrict__ b, const float* __restrict__ pos,
    float* __restrict__ xout, int mBase, int doLN,
    short (*As)[264])
{
    const int t = threadIdx.x;
    const int row = t >> 3, q8 = t & 7;      // 32 rows, 8 col-groups of 32
    const long gbase = (long)(mBase + row) * 256 + q8 * 32;
    float va[32];
    #pragma unroll
    for (int j = 0; j < 8; ++j) {
        float4 v = *(const float4*)(Ain + gbase + j * 4);
        va[j*4+0] = v.x; va[j*4+1] = v.y; va[j*4+2] = v.z; va[j*4+3] = v.w;
    }
    if (doLN) {
        float s1 = 0.f, s2 = 0.f;
        #pragma unroll
        for (int j = 0; j < 32; ++j) { s1 += va[j]; s2 += va[j] * va[j]; }
        s1 += __shfl_xor(s1, 1); s2 += __shfl_xor(s2, 1);
        s1 += __shfl_xor(s1, 2); s2 += __shfl_xor(s2, 2);
        s1 += __shfl_xor(s1, 4); s2 += __shfl_xor(s2, 4);
        const float mean = s1 * (1.f / 256.f);
        const float var  = s2 * (1.f / 256.f) - mean * mean;
        const float rstd = rsqrtf(var + 1e-5f);
        #pragma unroll
        for (int j = 0; j < 8; ++j) {
            float4 g4 = *(const float4*)(g + q8 * 32 + j * 4);
            float4 b4 = *(const float4*)(b + q8 * 32 + j * 4);
            va[j*4+0] = (va[j*4+0] - mean) * rstd * g4.x + b4.x;
            va[j*4+1] = (va[j*4+1] - mean) * rstd * g4.y + b4.y;
            va[j*4+2] = (va[j*4+2] - mean) * rstd * g4.z + b4.z;
            va[j*4+3] = (va[j*4+3] - mean) * rstd * g4.w + b4.w;
        }
    }
    if (xout) {
        #pragma unroll
        for (int j = 0; j < 8; ++j) {
            float4 v;
            v.x = va[j*4+0]; v.y = va[j*4+1]; v.z = va[j*4+2]; v.w = va[j*4+3];
            *(float4*)(xout + gbase + j * 4) = v;
        }
    }
    if (pos) {
        #pragma unroll
        for (int j = 0; j < 8; ++j) {
            float4 p = *(const float4*)(pos + gbase + j * 4);
            va[j*4+0] += p.x; va[j*4+1] += p.y; va[j*4+2] += p.z; va[j*4+3] += p.w;
        }
    }
    #pragma unroll
    for (int j8 = 0; j8 < 4; ++j8) {
        short tmp[8];
        #pragma unroll
        for (int e = 0; e < 8; ++e) tmp[e] = f2bf(va[j8 * 8 + e]);
        *(bf16x8*)&As[row][q8 * 32 + j8 * 8] = *(bf16x8*)tmp;
    }
}

// ============ 32-row GEMM core, A resident in LDS (K=256), B streamed ============
// Tile 32 x (NF*32). 4 waves: wr = wave>>1 (16-row half), wc = wave&1 (NF*16-col half).
template<int NF>
__device__ __forceinline__ void core32_Alds(
    const unsigned short* __restrict__ Bt, int nBase,
    const short (*As)[264], short (*Bs)[72], f32x4 (&acc)[NF])
{
    const int t = threadIdx.x;
    const int lane = t & 63, wave = t >> 6;
    const int wr = wave >> 1, wc = wave & 1;
    const int lr = lane & 15;

    #pragma unroll
    for (int j = 0; j < NF; ++j) acc[j] = (f32x4){0.f, 0.f, 0.f, 0.f};

    for (int k0 = 0; k0 < 256; k0 += 64) {
        bf16x8 rb[NF];
        #pragma unroll
        for (int q = 0; q < NF; ++q) {
            int flat = q * 256 + t, row = flat >> 3, cg = (flat & 7) * 8;
            rb[q] = *(const bf16x8*)(Bt + (long)(nBase + row) * 256 + k0 + cg);
        }
        __syncthreads();
        #pragma unroll
        for (int q = 0; q < NF; ++q) {
            int flat = q * 256 + t, row = flat >> 3, cg = (flat & 7) * 8;
            *(bf16x8*)&Bs[row][cg] = rb[q];
        }
        __syncthreads();
        #pragma unroll
        for (int kk = 0; kk < 2; ++kk) {
            const int lks = kk * 32 + (lane >> 4) * 8;
            bf16x8 af = *(const bf16x8*)&As[wr * 16 + lr][k0 + lks];
            #pragma unroll
            for (int fn = 0; fn < NF; ++fn) {
                bf16x8 bfr = *(bf16x8*)&Bs[wc * (NF * 16) + fn * 16 + lr][lks];
                acc[fn] = __builtin_amdgcn_mfma_f32_16x16x32_bf16(af, bfr, acc[fn], 0, 0, 0);
            }
        }
    }
}

// ============ 32-row GEMM core, A bf16 from global, B streamed ============
template<int NF>
__device__ __forceinline__ void core32_g(
    const unsigned short* __restrict__ A, const unsigned short* __restrict__ Bt,
    int K, int mBase, int nBase, short (*As)[72], short (*Bs)[72],
    f32x4 (&acc)[NF])
{
    const int t = threadIdx.x;
    const int lane = t & 63, wave = t >> 6;
    const int wr = wave >> 1, wc = wave & 1;
    const int lr = lane & 15;

    #pragma unroll
    for (int j = 0; j < NF; ++j) acc[j] = (f32x4){0.f, 0.f, 0.f, 0.f};

    for (int k0 = 0; k0 < K; k0 += 64) {
        bf16x8 ra, rb[NF];
        {
            int row = t >> 3, cg = (t & 7) * 8;
            ra = *(const bf16x8*)(A + (long)(mBase + row) * K + k0 + cg);
        }
        #pragma unroll
        for (int q = 0; q < NF; ++q) {
            int flat = q * 256 + t, row = flat >> 3, cg = (flat & 7) * 8;
            rb[q] = *(const bf16x8*)(Bt + (long)(nBase + row) * K + k0 + cg);
        }
        __syncthreads();
        {
            int row = t >> 3, cg = (t & 7) * 8;
            *(bf16x8*)&As[row][cg] = ra;
        }
        #pragma unroll
        for (int q = 0; q < NF; ++q) {
            int flat = q * 256 + t, row = flat >> 3, cg = (flat & 7) * 8;
            *(bf16x8*)&Bs[row][cg] = rb[q];
        }
        __syncthreads();
        #pragma unroll
        for (int kk = 0; kk < 2; ++kk) {
            const int lks = kk * 32 + (lane >> 4) * 8;
            bf16x8 af = *(bf16x8*)&As[wr * 16 + lr][lks];
            #pragma unroll
            for (int fn = 0; fn < NF; ++fn) {
                bf16x8 bfr = *(bf16x8*)&Bs[wc * (NF * 16) + fn * 16 + lr][lks];
                acc[fn] = __builtin_amdgcn_mfma_f32_16x16x32_bf16(af, bfr, acc[fn], 0, 0, 0);
            }
        }
    }
}

// ---------------- fused LN2 + projections (grid 170 x 5); 32-row tiles ----------------
__global__ __launch_bounds__(256) void proj_ln(
    const float* __restrict__ Ain, const float* __restrict__ pos,
    const float* __restrict__ g, const float* __restrict__ b,
    const unsigned short* __restrict__ WvT, const float* __restrict__ bv,
    const unsigned short* __restrict__ WofT, const float* __restrict__ bof,
    const unsigned short* __restrict__ WatT, const float* __restrict__ bat,
    unsigned short* __restrict__ value_bf, unsigned short* __restrict__ offraw,
    unsigned short* __restrict__ logits, float* __restrict__ xcur, int doLN)
{
    __shared__ short As[32][264];
    __shared__ short Bs[128][72];
    const int ny = blockIdx.y, mBase = blockIdx.x * 32;
    const unsigned short* Bp; const float* bias; int nBase, kind;
    if (ny < 2)      { Bp = WvT;  bias = bv;  nBase = ny * 128;       kind = 0; }
    else if (ny < 4) { Bp = WofT; bias = bof; nBase = (ny - 2) * 128; kind = 1; }
    else             { Bp = WatT; bias = bat; nBase = 0;              kind = 2; }

    prep_A32(Ain, g, b, (kind > 0) ? pos : nullptr,
             (doLN && ny == 0) ? xcur : nullptr, mBase, doLN, As);

    f32x4 acc[4];
    core32_Alds<4>(Bp, nBase, As, Bs, acc);

    const int lane = threadIdx.x & 63, wave = threadIdx.x >> 6;
    const int wr = wave >> 1, wc = wave & 1;
    #pragma unroll
    for (int fn = 0; fn < 4; ++fn)
        #pragma unroll
        for (int r = 0; r < 4; ++r) {
            int m = mBase + wr * 16 + (lane >> 4) * 4 + r;
            int n = nBase + wc * 64 + fn * 16 + (lane & 15);
            float v = acc[fn][r] + bias[n];
            if (kind == 0)      value_bf[(long)m * 256 + n] = (unsigned short)f2bf(v);
            else if (kind == 1) offraw[(long)m * 256 + n] = (unsigned short)f2bf(v);
            else                logits[(long)m * 128 + n] = (unsigned short)f2bf(v);
        }
}

// ---------------- fused LN1 + W1 GEMM + relu (grid 170 x 4, NF=8, 32x256 tile) ----------------
__global__ __launch_bounds__(256) void gemm_w1ln(
    const float* __restrict__ Ain, const float* __restrict__ g,
    const float* __restrict__ b, const unsigned short* __restrict__ W1T,
    const float* __restrict__ bias, unsigned short* __restrict__ hbuf,
    float* __restrict__ xout)
{
    __shared__ short As[32][264];
    __shared__ short Bs[256][72];
    const int mBase = blockIdx.x * 32, nBase = blockIdx.y * 256;

    prep_A32(Ain, g, b, nullptr, (blockIdx.y == 0) ? xout : nullptr, mBase, 1, As);

    f32x4 acc[8];
    core32_Alds<8>(W1T, nBase, As, Bs, acc);

    const int lane = threadIdx.x & 63, wave = threadIdx.x >> 6;
    const int wr = wave >> 1, wc = wave & 1;
    #pragma unroll
    for (int fn = 0; fn < 8; ++fn)
        #pragma unroll
        for (int r = 0; r < 4; ++r) {
            int m = mBase + wr * 16 + (lane >> 4) * 4 + r;
            int n = nBase + wc * 128 + fn * 16 + (lane & 15);
            float v = fmaxf(acc[fn][r] + bias[n], 0.f);
            hbuf[(long)m * 1024 + n] = (unsigned short)f2bf(v);
        }
}

// ---------------- plain GEMM (N=256) + bias + residual -> fp32 (grid 170 x 4, 32x64 tile) ----------------
__global__ __launch_bounds__(256) void gemm_res(
    const unsigned short* __restrict__ A, const unsigned short* __restrict__ Bt,
    const float* __restrict__ bias, const float* __restrict__ res,
    float* __restrict__ out, int K)
{
    __shared__ short As[32][72];
    __shared__ short Bs[64][72];
    const int mBase = blockIdx.x * 32, nBase = blockIdx.y * 64;
    f32x4 acc[2];
    core32_g<2>(A, Bt, K, mBase, nBase, As, Bs, acc);

    const int lane = threadIdx.x & 63, wave = threadIdx.x >> 6;
    const int wr = wave >> 1, wc = wave & 1;
    #pragma unroll
    for (int fn = 0; fn < 2; ++fn)
        #pragma unroll
        for (int r = 0; r < 4; ++r) {
            int m = mBase + wr * 16 + (lane >> 4) * 4 + r;
            int n = nBase + wc * 32 + fn * 16 + (lane & 15);
            out[(long)m * 256 + n] = acc[fn][r] + bias[n] + res[(long)m * 256 + n];
        }
}

// ---------------- MSDA sampling v5b: bf16 in/out, shfl reduce, coalesced ----------------
__global__ __launch_bounds__(256) void msda2(
    const unsigned short* __restrict__ value, const unsigned short* __restrict__ offraw,
    const unsigned short* __restrict__ logits, const float* __restrict__ vr,
    unsigned short* __restrict__ outB)
{
    const int t = threadIdx.x;
    const int q = t >> 7, tt = t & 127;
    const int s = blockIdx.x * 2 + q;

    __shared__ int4   sIdx[2][128];
    __shared__ float4 sW[2][128];

    {
        const int pt = tt & 15, l = pt >> 2;

        float lg = bf2f(logits[(long)s * 128 + tt]);
        float m = lg;
        #pragma unroll
        for (int o = 1; o < 16; o <<= 1) m = fmaxf(m, __shfl_xor(m, o));
        float e = expf(lg - m);
        float sum = e;
        #pragma unroll
        for (int o = 1; o < 16; o <<= 1) sum += __shfl_xor(sum, o);
        float aw = e / sum;

        int ls = (s < 4096) ? 0 : (s < 5120) ? 1 : (s < 5376) ? 2 : 3;
        int lw = c_logW[ls];
        int Wq = c_HW[ls];
        int rem = s - c_start[ls];
        int qi = rem >> lw, qj = rem & (Wq - 1);
        float xh = (qj + 0.5f) / (vr[ls * 2 + 1] * (float)Wq);
        float yh = (qi + 0.5f) / (vr[ls * 2 + 0] * (float)Wq);

        const int Wl = c_HW[l], sl = c_start[l];
        const float fW = (float)Wl;
        float refx = xh * vr[l * 2 + 1];
        float refy = yh * vr[l * 2 + 0];
        unsigned int uoxy = *(const unsigned int*)(offraw + (long)s * 256 + tt * 2);
        float ox = lo_f(uoxy), oy = hi_f(uoxy);
        float x = refx * fW + ox - 0.5f;
        float y = refy * fW + oy - 0.5f;
        float x0f = floorf(x), y0f = floorf(y);
        float fx = x - x0f, fy = y - y0f;
        int x0 = (int)x0f, y0 = (int)y0f;
        int x1 = x0 + 1, y1 = y0 + 1;
        float vx0 = (x0 >= 0 && x0 < Wl) ? 1.f : 0.f;
        float vx1 = (x1 >= 0 && x1 < Wl) ? 1.f : 0.f;
        float vy0 = (y0 >= 0 && y0 < Wl) ? 1.f : 0.f;
        float vy1 = (y1 >= 0 && y1 < Wl) ? 1.f : 0.f;
        int cx0 = min(max(x0, 0), Wl - 1), cx1 = min(max(x1, 0), Wl - 1);
        int cy0 = min(max(y0, 0), Wl - 1), cy1 = min(max(y1, 0), Wl - 1);

        int4 id4;
        id4.x = sl + cy0 * Wl + cx0;
        id4.y = sl + cy0 * Wl + cx1;
        id4.z = sl + cy1 * Wl + cx0;
        id4.w = sl + cy1 * Wl + cx1;
        sIdx[q][tt] = id4;
        float4 w4;
        w4.x = aw * (1.f - fx) * (1.f - fy) * vx0 * vy0;
        w4.y = aw * fx * (1.f - fy) * vx1 * vy0;
        w4.z = aw * (1.f - fx) * fy * vx0 * vy1;
        w4.w = aw * fx * fy * vx1 * vy1;
        sW[q][tt] = w4;
    }
    __syncthreads();

    // phase 2: h = tt>>4, pg = (tt>>2)&3, dq = tt&3 (dq fastest -> coalesced)
    const int h = tt >> 4, pg = (tt >> 2) & 3, dq = tt & 3;
    const int cb = h * 32 + dq * 8;

    float a8[8] = {0.f,0.f,0.f,0.f,0.f,0.f,0.f,0.f};
    #pragma unroll
    for (int p = 0; p < 4; ++p) {
        const int ei = h * 16 + pg * 4 + p;
        int4 id = sIdx[q][ei];
        float4 w = sW[q][ei];
        u32x4 u0 = *(const u32x4*)(value + (long)id.x * 256 + cb);
        u32x4 u1 = *(const u32x4*)(value + (long)id.y * 256 + cb);
        u32x4 u2 = *(const u32x4*)(value + (long)id.z * 256 + cb);
        u32x4 u3 = *(const u32x4*)(value + (long)id.w * 256 + cb);
        #pragma unroll
        for (int j = 0; j < 4; ++j) {
            a8[2*j]   += w.x * lo_f(u0[j]) + w.y * lo_f(u1[j])
                       + w.z * lo_f(u2[j]) + w.w * lo_f(u3[j]);
            a8[2*j+1] += w.x * hi_f(u0[j]) + w.y * hi_f(u1[j])
                       + w.z * hi_f(u2[j]) + w.w * hi_f(u3[j]);
        }
    }
    #pragma unroll
    for (int j = 0; j < 8; ++j) {
        a8[j] += __shfl_xor(a8[j], 4);
        a8[j] += __shfl_xor(a8[j], 8);
    }
    if (pg == 0) {
        short o8[8];
        #pragma unroll
        for (int j = 0; j < 8; ++j) o8[j] = f2bf(a8[j]);
        *(bf16x8*)(outB + (long)s * 256 + cb) = *(bf16x8*)o8;
    }
}

// ---------------- final LayerNorm: one wave per row ----------------
__global__ __launch_bounds__(256) void ln4f(
    const float* __restrict__ in, const float* __restrict__ g,
    const float* __restrict__ b, float* __restrict__ out)
{
    const int wave = threadIdx.x >> 6, lane = threadIdx.x & 63;
    const int s = blockIdx.x * 4 + wave;
    f32x4 v = *(const f32x4*)(in + (long)s * 256 + lane * 4);

    float sum = v[0] + v[1] + v[2] + v[3];
    #pragma unroll
    for (int o = 1; o < 64; o <<= 1) sum += __shfl_xor(sum, o);
    const float mean = sum * (1.f / 256.f);

    f32x4 d = v - mean;
    float sq = d[0]*d[0] + d[1]*d[1] + d[2]*d[2] + d[3]*d[3];
    #pragma unroll
    for (int o = 1; o < 64; o <<= 1) sq += __shfl_xor(sq, o);
    const float rstd = rsqrtf(sq * (1.f / 256.f) + 1e-5f);

    f32x4 gg = *(const f32x4*)(g + lane * 4);
    f32x4 bb = *(const f32x4*)(b + lane * 4);
    f32x4 o4 = d * rstd * gg + bb;
    *(f32x4*)(out + (long)s * 256 + lane * 4) = o4;
}

extern "C" void kernel_launch(void* const* d_in, const int* in_sizes, int n_in,
                              void* d_out, int out_size, void* d_ws, size_t ws_size,
                              hipStream_t stream) {
    const float* src   = (const float*)d_in[0];
    const float* pos   = (const float*)d_in[1];
    const float* vr    = (const float*)d_in[2];
    const float* Wv    = (const float*)d_in[5];
    const float* bv    = (const float*)d_in[6];
    const float* Woff  = (const float*)d_in[7];
    const float* boff  = (const float*)d_in[8];
    const float* Wattn = (const float*)d_in[9];
    const float* battn = (const float*)d_in[10];
    const float* Wout  = (const float*)d_in[11];
    const float* bout  = (const float*)d_in[12];
    const float* ln1g  = (const float*)d_in[13];
    const float* ln1b  = (const float*)d_in[14];
    const float* W1    = (const float*)d_in[15];
    const float* b1    = (const float*)d_in[16];
    const float* W2    = (const float*)d_in[17];
    const float* b2    = (const float*)d_in[18];
    const float* ln2g  = (const float*)d_in[19];
    const float* ln2b  = (const float*)d_in[20];

    const int S = S_TOT, C = C_DIM;
    const long SC = (long)S * C;

    // fp32 region
    float* ws     = (float*)d_ws;
    float* tmp2   = ws;                        // SC f32 (layer output, pre-LN2)
    float* xcur   = tmp2 + SC;                 // SC f32 (LN2 out = layer input x)
    float* xln1   = xcur + SC;                 // SC f32 (LN1 out, residual for W2)
    // bf16 region
    unsigned short* offraw_bf = (unsigned short*)(xln1 + SC);      // SC
    unsigned short* logits_bf = offraw_bf + SC;                    // S*128
    unsigned short* value_bf  = logits_bf + (long)S * 128;         // SC
    unsigned short* msda_bf   = value_bf + SC;                     // SC
    unsigned short* hbuf_bf   = msda_bf + SC;                      // S*F
    unsigned short* WT        = hbuf_bf + (long)S * F_DIM;         // 4521984

    const unsigned short* WvT  = WT + 0;
    const unsigned short* WofT = WT + 393216;
    const unsigned short* WatT = WT + 786432;
    const unsigned short* WouT = WT + 983040;
    const unsigned short* W1T  = WT + 1376256;
    const unsigned short* W2T  = WT + 2949120;

    prep_weights<<<1104, 256, 0, stream>>>(Wv, Woff, Wattn, Wout, W1, W2, WT);

    for (int i = 0; i < N_LAYERS; ++i) {
        const float* Ain = (i == 0) ? src : tmp2;
        const float* g2  = (i == 0) ? nullptr : ln2g + (long)(i - 1) * C;
        const float* bb2 = (i == 0) ? nullptr : ln2b + (long)(i - 1) * C;
        const float* resWout = (i == 0) ? src : xcur;

        proj_ln<<<dim3(170, 5), 256, 0, stream>>>(
            Ain, pos, g2, bb2,
            WvT + (long)i * 65536, bv + (long)i * C,
            WofT + (long)i * 65536, boff + (long)i * 256,
            WatT + (long)i * 32768, battn + (long)i * 128,
            value_bf, offraw_bf, logits_bf, xcur, (i == 0) ? 0 : 1);

        msda2<<<S / 2, 256, 0, stream>>>(value_bf, offraw_bf, logits_bf, vr, msda_bf);

        gemm_res<<<dim3(170, 4), 256, 0, stream>>>(
            msda_bf, WouT + (long)i * 65536, bout + (long)i * C, resWout, tmp2, 256);

        gemm_w1ln<<<dim3(170, 4), 256, 0, stream>>>(
            tmp2, ln1g + (long)i * C, ln1b + (long)i * C,
            W1T + (long)i * 262144, b1 + (long)i * F_DIM, hbuf_bf, xln1);

        gemm_res<<<dim3(170, 4), 256, 0, stream>>>(
            hbuf_bf, W2T + (long)i * 262144, b2 + (long)i * C, xln1, tmp2, 1024);
    }

    ln4f<<<S / 4, 256, 0, stream>>>(
        tmp2, ln2g + (long)(N_LAYERS - 1) * C, ln2b + (long)(N_LAYERS - 1) * C,
        (float*)d_out);
}